// Round 1
// baseline (566.712 us; speedup 1.0000x reference)
//
#include <hip/hip_runtime.h>

#define NNODES 50000
#define NEDGES 800000
#define NGRAPH 500
#define CH 100
#define CIN0 33
#define BN_EPS 1e-5f
#define NSHARD 8
#define SHSTRIDE 1024   // floats per shard: [4 layers][sum128|sq128]
#define PADE 950016     // NEDGES + 3*NNODES rounded up: CSR rows padded to mult of 4

#define SCAN_TPB 256
#define SCAN_IPT 4
#define SCAN_TILE (SCAN_TPB * SCAN_IPT)
#define SCAN_BLOCKS ((NNODES + SCAN_TILE - 1) / SCAN_TILE)

// pack two fp32 into (bf16(x) | bf16(y)<<16), round-to-nearest-even
__device__ inline unsigned pack_bf16(float x, float y) {
    unsigned xb = __float_as_uint(x);
    unsigned yb = __float_as_uint(y);
    xb += 0x7FFF + ((xb >> 16) & 1);
    yb += 0x7FFF + ((yb >> 16) & 1);
    return (xb >> 16) | (yb & 0xFFFF0000u);
}
__device__ inline float unp_lo(unsigned v) { return __uint_as_float(v << 16); }
__device__ inline float unp_hi(unsigned v) { return __uint_as_float(v & 0xFFFF0000u); }

// ---------------- init: zero counters + BN stat shards + pool accumulator; sentinel-fill edge arrays ----------------
__global__ void k_init(int* __restrict__ cnt, float* __restrict__ stats,
                       float* __restrict__ gbuf, int* __restrict__ ew0,
                       int* __restrict__ ewc) {
    int i = blockIdx.x * blockDim.x + threadIdx.x;
    if (i < NNODES) cnt[i] = 0;
    if (i < NGRAPH * CH) gbuf[i] = 0.f;   // NGRAPH*CH == NNODES
    if (i < NSHARD * SHSTRIDE) stats[i] = 0.f;
    if (i < PADE) { ew0[i] = NNODES * 68; ewc[i] = NNODES * 200; }  // sentinel: zero row
}

// ---------------- in-degree histogram over dst ----------------
__global__ void k_hist(const int* __restrict__ dst, int* __restrict__ cnt) {
    int e = blockIdx.x * blockDim.x + threadIdx.x;
    if (e < NEDGES) atomicAdd(&cnt[dst[e]], 1);
}

// ---------------- pack dinv[r]*x into bf16 rows of 17 uints (+1 zero sentinel row) ----------------
__global__ void k_packx(const float* __restrict__ x, unsigned* __restrict__ xb,
                        const float* __restrict__ dinv) {
    int i = blockIdx.x * blockDim.x + threadIdx.x;
    if (i >= (NNODES + 1) * 17) return;
    int r = i / 17, s = i - r * 17;
    if (r >= NNODES) { xb[i] = 0u; return; }
    float di = dinv[r];
    float a = di * x[r * CIN0 + 2 * s];
    float b = (2 * s + 1 < CIN0) ? di * x[r * CIN0 + 2 * s + 1] : 0.f;
    xb[i] = pack_bf16(a, b);
}

// ---------------- exclusive scan of padded counts -> rowptr; also dinv = rsqrt(cnt+1) ----------------
__global__ void k_scan1(const int* __restrict__ cnt, int* __restrict__ rowptr,
                        int* __restrict__ blkSums, float* __restrict__ dinv) {
    __shared__ int ts[SCAN_TPB];
    int tid = threadIdx.x;
    int base = blockIdx.x * SCAN_TILE + tid * SCAN_IPT;
    int v[SCAN_IPT];
    int s = 0;
    #pragma unroll
    for (int j = 0; j < SCAN_IPT; ++j) {
        int i = base + j;
        int c = (i < NNODES) ? cnt[i] : 0;
        if (i < NNODES) dinv[i] = rsqrtf((float)(c + 1));
        v[j] = (c + 3) & ~3;   // pad each row to multiple of 4 edges
        s += v[j];
    }
    ts[tid] = s;
    __syncthreads();
    for (int off = 1; off < SCAN_TPB; off <<= 1) {
        int add = (tid >= off) ? ts[tid - off] : 0;
        __syncthreads();
        ts[tid] += add;
        __syncthreads();
    }
    int run = ts[tid] - s;  // exclusive prefix within block
    #pragma unroll
    for (int j = 0; j < SCAN_IPT; ++j) {
        int i = base + j;
        if (i < NNODES) rowptr[i] = run;
        run += v[j];
    }
    if (tid == SCAN_TPB - 1) blkSums[blockIdx.x] = ts[tid];
}

__global__ void k_scan2(const int* __restrict__ blkSums, int* __restrict__ blkOff,
                        int* __restrict__ rowptr) {
    if (threadIdx.x == 0) {
        int run = 0;
        for (int i = 0; i < SCAN_BLOCKS; ++i) { blkOff[i] = run; run += blkSums[i]; }
        rowptr[NNODES] = run;   // total padded edges
    }
}

__global__ void k_scan3(int* __restrict__ rowptr, int* __restrict__ cursor,
                        const int* __restrict__ blkOff) {
    int off = blkOff[blockIdx.x];
    int base = blockIdx.x * SCAN_TILE + threadIdx.x * SCAN_IPT;
    #pragma unroll
    for (int j = 0; j < SCAN_IPT; ++j) {
        int i = base + j;
        if (i < NNODES) {
            int vv = rowptr[i] + off;
            rowptr[i] = vv;
            cursor[i] = vv;
        }
    }
}

// ---------------- scatter edges into padded CSR (by dst); store byte offsets of src rows ----------------
__global__ void k_scatter(const int* __restrict__ src, const int* __restrict__ dst,
                          int* __restrict__ cursor, int* __restrict__ ew0,
                          int* __restrict__ ewc) {
    int e = blockIdx.x * blockDim.x + threadIdx.x;
    if (e < NEDGES) {
        int d = dst[e], s = src[e];
        int pos = atomicAdd(&cursor[d], 1);
        ew0[pos] = s * 68;    // byte offset into xb  (17 uints/row)
        ewc[pos] = s * 200;   // byte offset into Y   (50 uints/row)
    }
}

// ---------------- apply y = dinv * relu(BN(z)) in bf16, one streaming pass ----------------
__global__ __launch_bounds__(256) void k_bnact(
    const unsigned* __restrict__ Zb, unsigned* __restrict__ Y,
    const float* __restrict__ gsum, const float* __restrict__ gsq,
    const float* __restrict__ gamma, const float* __restrict__ beta,
    const float* __restrict__ dinv) {
    int i = blockIdx.x * blockDim.x + threadIdx.x;
    if (i >= (NNODES + 1) * 50) return;
    int node = i / 50, c = i - node * 50;
    if (node >= NNODES) { Y[i] = 0u; return; }   // zero sentinel row
    float sx = 0.f, sy = 0.f, qx = 0.f, qy = 0.f;
    #pragma unroll
    for (int sh = 0; sh < NSHARD; ++sh) {
        float2 s2 = ((const float2*)(gsum + sh * SHSTRIDE))[c];
        float2 q2 = ((const float2*)(gsq + sh * SHSTRIDE))[c];
        sx += s2.x; sy += s2.y; qx += q2.x; qy += q2.y;
    }
    constexpr float invN = 1.f / NNODES;
    float2 g2 = ((const float2*)gamma)[c];
    float2 b2 = ((const float2*)beta)[c];
    float mx = sx * invN, my = sy * invN;
    float vx = qx * invN - mx * mx, vy = qy * invN - my * my;
    float scx = g2.x * rsqrtf(vx + BN_EPS), shx = b2.x - mx * scx;
    float scy = g2.y * rsqrtf(vy + BN_EPS), shy = b2.y - my * scy;
    float di = dinv[node];
    unsigned v = Zb[i];
    float yx = fmaxf(unp_lo(v) * scx + shx, 0.f) * di;
    float yy = fmaxf(unp_hi(v) * scy + shy, 0.f) * di;
    Y[i] = pack_bf16(yx, yy);
}

// ---------------- pure gather-add aggregate over pre-scaled bf16 rows ----------------
// a_i = dinv_i * ( sum_e y'[src] + y'[i] ) with y' already dinv*activation-scaled.
// Edge list is row-padded to mult-of-4 with a zero sentinel row -> branch-free
// uniform int4 broadcast loads of 4 byte-offsets at a time; no shuffles, no BN.
template<int CPACK, int OS, bool OBF>
__global__ __launch_bounds__(256) void k_gather(
    const unsigned* __restrict__ h, void* __restrict__ aout,
    const int* __restrict__ rowptr, const int* __restrict__ ew,
    const float* __restrict__ dinv) {
    int node = (blockIdx.x * 256 + threadIdx.x) >> 6;
    int lane = threadIdx.x & 63;
    if (node >= NNODES) return;
    int p0 = rowptr[node], p1 = rowptr[node + 1];
    float di = dinv[node];
    bool act = lane < CPACK;
    int l4 = lane << 2;
    const char* hb = (const char*)h;
    float ax = 0.f, ay = 0.f;
    if (act) {
        unsigned hv = h[node * CPACK + lane];   // self term (already dinv-scaled)
        ax = unp_lo(hv); ay = unp_hi(hv);
    }
    const int4* E = (const int4*)ew + (p0 >> 2);
    int n4 = (p1 - p0) >> 2;
    #pragma unroll 2
    for (int q = 0; q < n4; ++q) {
        int4 es = E[q];                         // wave-uniform broadcast load
        if (act) {
            unsigned v0 = *(const unsigned*)(hb + (unsigned)(es.x + l4));
            unsigned v1 = *(const unsigned*)(hb + (unsigned)(es.y + l4));
            unsigned v2 = *(const unsigned*)(hb + (unsigned)(es.z + l4));
            unsigned v3 = *(const unsigned*)(hb + (unsigned)(es.w + l4));
            ax += unp_lo(v0); ay += unp_hi(v0);
            ax += unp_lo(v1); ay += unp_hi(v1);
            ax += unp_lo(v2); ay += unp_hi(v2);
            ax += unp_lo(v3); ay += unp_hi(v3);
        }
    }
    float ox = di * ax, oy = di * ay;
    if constexpr (OBF) {
        if (lane < OS)
            ((unsigned*)aout)[(size_t)node * OS + lane] = pack_bf16(ox, oy);
    } else {
        if (lane < (OS + 1) / 2)
            ((float2*)((float*)aout + (size_t)node * OS))[lane] = make_float2(ox, oy);
    }
}

// ---------------- CH-layer GEMM (512 thr, 4x4 tile; R14 hot loop) ----------------
__global__ __launch_bounds__(512) void k_gemm_ch(
    const unsigned* __restrict__ Ab, const float* __restrict__ W,
    const float* __restrict__ bias, unsigned* __restrict__ Zb,
    float* __restrict__ gsum, float* __restrict__ gsq) {
    __shared__ __align__(16) float wS[CH * CH];   // 40 KB
    __shared__ __align__(16) float aS[64 * CH];   // 25.6 KB
    __shared__ float sSum[CH], sSq[CH];
    int tid = threadIdx.x;
    for (int i = tid; i < CH; i += 512) { sSum[i] = 0.f; sSq[i] = 0.f; }
    for (int i = tid; i < CH * CH; i += 512) wS[i] = W[i];
    int row0 = blockIdx.x * 64;
    {
        const unsigned* As = Ab + (size_t)row0 * 50;
        int maxI = (NNODES - row0) * 50;   // >= 3200 except last block
        for (int i = tid; i < 64 * 50; i += 512) {
            unsigned v = (i < maxI) ? As[i] : 0u;
            ((float2*)aS)[i] = make_float2(unp_lo(v), unp_hi(v));
        }
    }
    __syncthreads();
    if (tid < 400) {
        int ct = tid % 25, rt = tid / 25;  // ct 0..24, rt 0..15
        int c0 = ct * 4, r0 = rt * 4;
        float acc[4][4] = {};
        for (int k = 0; k < CH; k += 4) {
            float4 w0 = *(const float4*)&wS[(k + 0) * CH + c0];
            float4 w1 = *(const float4*)&wS[(k + 1) * CH + c0];
            float4 w2 = *(const float4*)&wS[(k + 2) * CH + c0];
            float4 w3 = *(const float4*)&wS[(k + 3) * CH + c0];
            #pragma unroll
            for (int j = 0; j < 4; ++j) {
                float4 av = *(const float4*)&aS[(r0 + j) * CH + k];
                acc[j][0] += av.x * w0.x + av.y * w1.x + av.z * w2.x + av.w * w3.x;
                acc[j][1] += av.x * w0.y + av.y * w1.y + av.z * w2.y + av.w * w3.y;
                acc[j][2] += av.x * w0.z + av.y * w1.z + av.z * w2.z + av.w * w3.z;
                acc[j][3] += av.x * w0.w + av.y * w1.w + av.z * w2.w + av.w * w3.w;
            }
        }
        float4 bv = *(const float4*)&bias[c0];
        float cs0 = 0, cs1 = 0, cs2 = 0, cs3 = 0, cq0 = 0, cq1 = 0, cq2 = 0, cq3 = 0;
        #pragma unroll
        for (int j = 0; j < 4; ++j) {
            int r = row0 + r0 + j;
            if (r < NNODES) {
                float z0 = acc[j][0] + bv.x, z1 = acc[j][1] + bv.y;
                float z2 = acc[j][2] + bv.z, z3 = acc[j][3] + bv.w;
                *(uint2*)&Zb[(size_t)r * 50 + (c0 >> 1)] =
                    make_uint2(pack_bf16(z0, z1), pack_bf16(z2, z3));
                cs0 += z0; cs1 += z1; cs2 += z2; cs3 += z3;
                cq0 += z0 * z0; cq1 += z1 * z1; cq2 += z2 * z2; cq3 += z3 * z3;
            }
        }
        atomicAdd(&sSum[c0], cs0); atomicAdd(&sSum[c0 + 1], cs1);
        atomicAdd(&sSum[c0 + 2], cs2); atomicAdd(&sSum[c0 + 3], cs3);
        atomicAdd(&sSq[c0], cq0); atomicAdd(&sSq[c0 + 1], cq1);
        atomicAdd(&sSq[c0 + 2], cq2); atomicAdd(&sSq[c0 + 3], cq3);
    }
    __syncthreads();
    int sh = (blockIdx.x & (NSHARD - 1)) * SHSTRIDE;
    if (tid < CH) { atomicAdd(&gsum[sh + tid], sSum[tid]); atomicAdd(&gsq[sh + tid], sSq[tid]); }
}

// ---------------- layer-0 GEMM (512 thr, 4x4 tile, K=36, unroll-capped) ----------------
__global__ __launch_bounds__(512) void k_gemm0(
    const float* __restrict__ A, const float* __restrict__ W, const float* __restrict__ bias,
    unsigned* __restrict__ Zb, float* __restrict__ gsum, float* __restrict__ gsq) {
    constexpr int K = CIN0, KP = 36;
    __shared__ __align__(16) float wS[KP * CH];   // 14.4 KB
    __shared__ __align__(16) float aS[64 * KP];   // 9.2 KB
    __shared__ float sSum[CH], sSq[CH];
    int tid = threadIdx.x;
    for (int i = tid; i < CH; i += 512) { sSum[i] = 0.f; sSq[i] = 0.f; }
    for (int i = tid; i < KP * CH; i += 512) wS[i] = (i < K * CH) ? W[i] : 0.f;
    int row0 = blockIdx.x * 64;
    {
        const float* As = A + (size_t)row0 * KP;
        int maxI = (NNODES - row0) * KP;
        for (int i = tid; i < 64 * KP; i += 512) aS[i] = (i < maxI) ? As[i] : 0.f;
    }
    __syncthreads();
    if (tid < 400) {
        int ct = tid % 25, rt = tid / 25;  // ct 0..24, rt 0..15
        int c0 = ct * 4, r0 = rt * 4;
        float acc[4][4] = {};
        #pragma unroll 1
        for (int k = 0; k < KP; k += 4) {
            float4 w0 = *(const float4*)&wS[(k + 0) * CH + c0];
            float4 w1 = *(const float4*)&wS[(k + 1) * CH + c0];
            float4 w2 = *(const float4*)&wS[(k + 2) * CH + c0];
            float4 w3 = *(const float4*)&wS[(k + 3) * CH + c0];
            #pragma unroll
            for (int j = 0; j < 4; ++j) {
                float4 av = *(const float4*)&aS[(r0 + j) * KP + k];
                acc[j][0] += av.x * w0.x + av.y * w1.x + av.z * w2.x + av.w * w3.x;
                acc[j][1] += av.x * w0.y + av.y * w1.y + av.z * w2.y + av.w * w3.y;
                acc[j][2] += av.x * w0.z + av.y * w1.z + av.z * w2.z + av.w * w3.z;
                acc[j][3] += av.x * w0.w + av.y * w1.w + av.z * w2.w + av.w * w3.w;
            }
        }
        float4 bv = *(const float4*)&bias[c0];
        float cs0 = 0, cs1 = 0, cs2 = 0, cs3 = 0, cq0 = 0, cq1 = 0, cq2 = 0, cq3 = 0;
        #pragma unroll
        for (int j = 0; j < 4; ++j) {
            int r = row0 + r0 + j;
            if (r < NNODES) {
                float z0 = acc[j][0] + bv.x, z1 = acc[j][1] + bv.y;
                float z2 = acc[j][2] + bv.z, z3 = acc[j][3] + bv.w;
                *(uint2*)&Zb[(size_t)r * 50 + (c0 >> 1)] =
                    make_uint2(pack_bf16(z0, z1), pack_bf16(z2, z3));
                cs0 += z0; cs1 += z1; cs2 += z2; cs3 += z3;
                cq0 += z0 * z0; cq1 += z1 * z1; cq2 += z2 * z2; cq3 += z3 * z3;
            }
        }
        atomicAdd(&sSum[c0], cs0); atomicAdd(&sSum[c0 + 1], cs1);
        atomicAdd(&sSum[c0 + 2], cs2); atomicAdd(&sSum[c0 + 3], cs3);
        atomicAdd(&sSq[c0], cq0); atomicAdd(&sSq[c0 + 1], cq1);
        atomicAdd(&sSq[c0 + 2], cq2); atomicAdd(&sSq[c0 + 3], cq3);
    }
    __syncthreads();
    int sh = (blockIdx.x & (NSHARD - 1)) * SHSTRIDE;
    if (tid < CH) { atomicAdd(&gsum[sh + tid], sSum[tid]); atomicAdd(&gsq[sh + tid], sSq[tid]); }
}

// ---------------- global_add_pool of BN(z) from bf16 Z; 4 row-chunks per graph ----------------
__global__ void k_pool(const unsigned* __restrict__ Zl, const int* __restrict__ batch,
                       const float* __restrict__ gsum, const float* __restrict__ gsq,
                       const float* __restrict__ gamma, const float* __restrict__ beta,
                       float* __restrict__ g) {
    int gid = blockIdx.x;
    int part = blockIdx.y;
    int lo = 0, hi = NNODES;
    while (lo < hi) { int mid = (lo + hi) >> 1; if (batch[mid] < gid) lo = mid + 1; else hi = mid; }
    int start = lo;
    hi = NNODES;
    while (lo < hi) { int mid = (lo + hi) >> 1; if (batch[mid] < gid + 1) lo = mid + 1; else hi = mid; }
    int end = lo;
    int len = end - start;
    int cb = (len + 3) >> 2;
    int s = start + part * cb;
    int e = s + cb; if (e > end) e = end;
    if (s >= e) return;
    int t = threadIdx.x;
    if (t >= 50) return;
    float su = 0.f, sv = 0.f, qu = 0.f, qv = 0.f;
    #pragma unroll
    for (int sh = 0; sh < NSHARD; ++sh) {
        float2 s2 = ((const float2*)(gsum + sh * SHSTRIDE))[t];
        float2 q2 = ((const float2*)(gsq + sh * SHSTRIDE))[t];
        su += s2.x; sv += s2.y; qu += q2.x; qv += q2.y;
    }
    constexpr float invN = 1.f / NNODES;
    float2 g2 = ((const float2*)gamma)[t];
    float2 b2 = ((const float2*)beta)[t];
    float mx = su * invN, my = sv * invN;
    float vx = qu * invN - mx * mx, vy = qv * invN - my * my;
    float scx = g2.x * rsqrtf(vx + BN_EPS), shx = b2.x - mx * scx;
    float scy = g2.y * rsqrtf(vy + BN_EPS), shy = b2.y - my * scy;
    float sx = 0.f, sy = 0.f;
    for (int r = s; r < e; ++r) {
        unsigned v = Zl[(size_t)r * 50 + t];
        sx += unp_lo(v); sy += unp_hi(v);
    }
    float n = (float)(e - s);
    atomicAdd(&g[gid * CH + 2 * t], sx * scx + n * shx);
    atomicAdd(&g[gid * CH + 2 * t + 1], sy * scy + n * shy);
}

// ---------------- out = leakyrelu(g @ Wout + bout, 0.1) ----------------
__global__ __launch_bounds__(256) void k_out(const float* __restrict__ g,
                                             const float* __restrict__ Wout,
                                             const float* __restrict__ bout,
                                             float* __restrict__ out) {
    __shared__ float gS[CH];
    int gid = blockIdx.x, tid = threadIdx.x;
    if (tid < CH) gS[tid] = g[gid * CH + tid];
    __syncthreads();
    if (tid >= 200) return;
    float acc = bout[tid];
    for (int k = 0; k < CH; ++k) acc += gS[k] * Wout[k * 200 + tid];
    out[gid * 200 + tid] = acc > 0.f ? acc : 0.1f * acc;
}

extern "C" void kernel_launch(void* const* d_in, const int* in_sizes, int n_in,
                              void* d_out, int out_size, void* d_ws, size_t ws_size,
                              hipStream_t stream) {
    const float* x = (const float*)d_in[0];
    const int* ei = (const int*)d_in[1];
    const int* batch = (const int*)d_in[2];
    const float* W0 = (const float*)d_in[3];
    const float* Wrest = (const float*)d_in[4];
    const float* b = (const float*)d_in[5];
    const float* gamma = (const float*)d_in[6];
    const float* beta = (const float*)d_in[7];
    const float* Wout = (const float*)d_in[8];
    const float* bout = (const float*)d_in[9];
    float* out = (float*)d_out;
    const int* srcA = ei;
    const int* dstA = ei + NEDGES;

    char* wsb = (char*)d_ws;
    size_t off = 0;
    auto alloc = [&](size_t elems) -> void* {
        void* p = (void*)(wsb + off);
        off += ((elems + 7) & ~(size_t)7) * 4;
        return p;
    };
    int* cnt = (int*)alloc(NNODES);
    int* rowptr = (int*)alloc(NNODES + 1);
    int* cursor = (int*)alloc(NNODES);
    float* dinv = (float*)alloc(NNODES);
    int* scanBlk = (int*)alloc(64);
    int* scanOff = (int*)alloc(64);
    float* stats = (float*)alloc(NSHARD * SHSTRIDE);  // per shard: [l*128]=sum, [512+l*128]=sq
    int* ew0 = (int*)alloc(PADE);                      // byte offsets into xb
    int* ewc = (int*)alloc(PADE);                      // byte offsets into Y
    unsigned* xb = (unsigned*)alloc((size_t)(NNODES + 1) * 17);
    // union: A0 (fp32, N*36 = 1.8M words, layer-0 only) / Y (bf16, (N+1)*50 = 2.5M words, layers 1-3)
    float* A0 = (float*)alloc((size_t)(NNODES + 1) * 50);
    unsigned* Y = (unsigned*)A0;
    unsigned* Abf = (unsigned*)alloc((size_t)NNODES * 50);
    unsigned* Zb = (unsigned*)alloc((size_t)NNODES * 50);
    float* gbuf = (float*)alloc((size_t)NGRAPH * CH);
    (void)ws_size; (void)n_in; (void)in_sizes; (void)out_size;

    hipLaunchKernelGGL(k_init, dim3((PADE + 255) / 256), dim3(256), 0, stream,
                       cnt, stats, gbuf, ew0, ewc);
    hipLaunchKernelGGL(k_hist, dim3((NEDGES + 255) / 256), dim3(256), 0, stream, dstA, cnt);
    hipLaunchKernelGGL(k_scan1, dim3(SCAN_BLOCKS), dim3(SCAN_TPB), 0, stream, cnt, rowptr, scanBlk, dinv);
    hipLaunchKernelGGL(k_scan2, dim3(1), dim3(64), 0, stream, scanBlk, scanOff, rowptr);
    hipLaunchKernelGGL(k_scan3, dim3(SCAN_BLOCKS), dim3(SCAN_TPB), 0, stream, rowptr, cursor, scanOff);
    hipLaunchKernelGGL(k_packx, dim3(((NNODES + 1) * 17 + 255) / 256), dim3(256), 0, stream,
                       x, xb, dinv);
    hipLaunchKernelGGL(k_scatter, dim3((NEDGES + 255) / 256), dim3(256), 0, stream,
                       srcA, dstA, cursor, ew0, ewc);

    // ---- layer 0 ----
    hipLaunchKernelGGL((k_gather<17, 36, false>), dim3(12500), dim3(256), 0, stream,
                       xb, A0, rowptr, ew0, dinv);
    hipLaunchKernelGGL(k_gemm0, dim3((NNODES + 63) / 64), dim3(512), 0, stream,
                       A0, W0, b, Zb, stats + 0 * 128, stats + 512 + 0 * 128);
    // ---- layers 1..3 ----
    for (int l = 1; l < 4; ++l) {
        float* ps = stats + (l - 1) * 128;
        float* pq = stats + 512 + (l - 1) * 128;
        hipLaunchKernelGGL(k_bnact, dim3(((NNODES + 1) * 50 + 255) / 256), dim3(256), 0, stream,
                           Zb, Y, ps, pq, gamma + (l - 1) * CH, beta + (l - 1) * CH, dinv);
        hipLaunchKernelGGL((k_gather<50, 50, true>), dim3(12500), dim3(256), 0, stream,
                           Y, Abf, rowptr, ewc, dinv);
        hipLaunchKernelGGL(k_gemm_ch, dim3((NNODES + 63) / 64), dim3(512), 0, stream,
                           Abf, Wrest + (l - 1) * 10000, b + l * CH, Zb,
                           stats + l * 128, stats + 512 + l * 128);
    }
    hipLaunchKernelGGL(k_pool, dim3(NGRAPH, 4), dim3(64), 0, stream, Zb, batch,
                       stats + 3 * 128, stats + 512 + 3 * 128, gamma + 3 * CH, beta + 3 * CH, gbuf);
    hipLaunchKernelGGL(k_out, dim3(NGRAPH), dim3(256), 0, stream, gbuf, Wout, bout, out);
}

// Round 2
// 545.560 us; speedup vs baseline: 1.0388x; 1.0388x over previous
//
#include <hip/hip_runtime.h>

#define NNODES 50000
#define NEDGES 800000
#define NGRAPH 500
#define CH 100
#define CIN0 33
#define BN_EPS 1e-5f
#define NSHARD 8
#define SHSTRIDE 1024   // floats per shard: [4 layers][sum128|sq128]
#define PADE 1152000    // >= NEDGES + 7*NNODES: CSR rows padded to mult of 8

#define SCAN_TPB 256
#define SCAN_IPT 4
#define SCAN_TILE (SCAN_TPB * SCAN_IPT)
#define SCAN_BLOCKS ((NNODES + SCAN_TILE - 1) / SCAN_TILE)

// pack two fp32 into (bf16(x) | bf16(y)<<16), round-to-nearest-even
__device__ inline unsigned pack_bf16(float x, float y) {
    unsigned xb = __float_as_uint(x);
    unsigned yb = __float_as_uint(y);
    xb += 0x7FFF + ((xb >> 16) & 1);
    yb += 0x7FFF + ((yb >> 16) & 1);
    return (xb >> 16) | (yb & 0xFFFF0000u);
}
__device__ inline float unp_lo(unsigned v) { return __uint_as_float(v << 16); }
__device__ inline float unp_hi(unsigned v) { return __uint_as_float(v & 0xFFFF0000u); }

// ---------------- init: zero counters + BN stat shards + pool accumulator; sentinel-fill edge array ----------------
__global__ void k_init(int* __restrict__ cnt, float* __restrict__ stats,
                       float* __restrict__ gbuf, unsigned* __restrict__ ew) {
    int i = blockIdx.x * blockDim.x + threadIdx.x;
    if (i < NNODES) cnt[i] = 0;
    if (i < NGRAPH * CH) gbuf[i] = 0.f;   // NGRAPH*CH == NNODES
    if (i < NSHARD * SHSTRIDE) stats[i] = 0.f;
    if (i < PADE) ew[i] = NNODES;         // sentinel: zero row
}

// ---------------- in-degree histogram over dst ----------------
__global__ void k_hist(const int* __restrict__ dst, int* __restrict__ cnt) {
    int e = blockIdx.x * blockDim.x + threadIdx.x;
    if (e < NEDGES) atomicAdd(&cnt[dst[e]], 1);
}

// ---------------- pack dinv[r]*x into bf16 rows of 17 uints (+1 zero sentinel row) ----------------
__global__ void k_packx(const float* __restrict__ x, unsigned* __restrict__ xb,
                        const float* __restrict__ dinv) {
    int i = blockIdx.x * blockDim.x + threadIdx.x;
    if (i >= (NNODES + 1) * 17) return;
    int r = i / 17, s = i - r * 17;
    if (r >= NNODES) { xb[i] = 0u; return; }
    float di = dinv[r];
    float a = di * x[r * CIN0 + 2 * s];
    float b = (2 * s + 1 < CIN0) ? di * x[r * CIN0 + 2 * s + 1] : 0.f;
    xb[i] = pack_bf16(a, b);
}

// ---------------- exclusive scan of padded counts -> rowptr; also dinv = rsqrt(cnt+1) ----------------
__global__ void k_scan1(const int* __restrict__ cnt, int* __restrict__ rowptr,
                        int* __restrict__ blkSums, float* __restrict__ dinv) {
    __shared__ int ts[SCAN_TPB];
    int tid = threadIdx.x;
    int base = blockIdx.x * SCAN_TILE + tid * SCAN_IPT;
    int v[SCAN_IPT];
    int s = 0;
    #pragma unroll
    for (int j = 0; j < SCAN_IPT; ++j) {
        int i = base + j;
        int c = (i < NNODES) ? cnt[i] : 0;
        if (i < NNODES) dinv[i] = rsqrtf((float)(c + 1));
        v[j] = (c + 7) & ~7;   // pad each row to multiple of 8 edges
        s += v[j];
    }
    ts[tid] = s;
    __syncthreads();
    for (int off = 1; off < SCAN_TPB; off <<= 1) {
        int add = (tid >= off) ? ts[tid - off] : 0;
        __syncthreads();
        ts[tid] += add;
        __syncthreads();
    }
    int run = ts[tid] - s;  // exclusive prefix within block
    #pragma unroll
    for (int j = 0; j < SCAN_IPT; ++j) {
        int i = base + j;
        if (i < NNODES) rowptr[i] = run;
        run += v[j];
    }
    if (tid == SCAN_TPB - 1) blkSums[blockIdx.x] = ts[tid];
}

__global__ void k_scan2(const int* __restrict__ blkSums, int* __restrict__ blkOff,
                        int* __restrict__ rowptr) {
    if (threadIdx.x == 0) {
        int run = 0;
        for (int i = 0; i < SCAN_BLOCKS; ++i) { blkOff[i] = run; run += blkSums[i]; }
        rowptr[NNODES] = run;   // total padded edges
    }
}

__global__ void k_scan3(int* __restrict__ rowptr, int* __restrict__ cursor,
                        const int* __restrict__ blkOff) {
    int off = blkOff[blockIdx.x];
    int base = blockIdx.x * SCAN_TILE + threadIdx.x * SCAN_IPT;
    #pragma unroll
    for (int j = 0; j < SCAN_IPT; ++j) {
        int i = base + j;
        if (i < NNODES) {
            int vv = rowptr[i] + off;
            rowptr[i] = vv;
            cursor[i] = vv;
        }
    }
}

// ---------------- scatter edges into padded CSR (by dst); store src node index (single 4B store) ----------------
__global__ void k_scatter(const int* __restrict__ src, const int* __restrict__ dst,
                          int* __restrict__ cursor, unsigned* __restrict__ ew) {
    int e = blockIdx.x * blockDim.x + threadIdx.x;
    if (e < NEDGES) {
        int d = dst[e], s = src[e];
        int pos = atomicAdd(&cursor[d], 1);
        ew[pos] = (unsigned)s;
    }
}

// ---------------- apply y = dinv * relu(BN(z)) in bf16, one streaming pass ----------------
__global__ __launch_bounds__(256) void k_bnact(
    const unsigned* __restrict__ Zb, unsigned* __restrict__ Y,
    const float* __restrict__ gsum, const float* __restrict__ gsq,
    const float* __restrict__ gamma, const float* __restrict__ beta,
    const float* __restrict__ dinv) {
    int i = blockIdx.x * blockDim.x + threadIdx.x;
    if (i >= (NNODES + 1) * 50) return;
    int node = i / 50, c = i - node * 50;
    if (node >= NNODES) { Y[i] = 0u; return; }   // zero sentinel row
    float sx = 0.f, sy = 0.f, qx = 0.f, qy = 0.f;
    #pragma unroll
    for (int sh = 0; sh < NSHARD; ++sh) {
        float2 s2 = ((const float2*)(gsum + sh * SHSTRIDE))[c];
        float2 q2 = ((const float2*)(gsq + sh * SHSTRIDE))[c];
        sx += s2.x; sy += s2.y; qx += q2.x; qy += q2.y;
    }
    constexpr float invN = 1.f / NNODES;
    float2 g2 = ((const float2*)gamma)[c];
    float2 b2 = ((const float2*)beta)[c];
    float mx = sx * invN, my = sy * invN;
    float vx = qx * invN - mx * mx, vy = qy * invN - my * my;
    float scx = g2.x * rsqrtf(vx + BN_EPS), shx = b2.x - mx * scx;
    float scy = g2.y * rsqrtf(vy + BN_EPS), shy = b2.y - my * scy;
    float di = dinv[node];
    unsigned v = Zb[i];
    float yx = fmaxf(unp_lo(v) * scx + shx, 0.f) * di;
    float yy = fmaxf(unp_hi(v) * scy + shy, 0.f) * di;
    Y[i] = pack_bf16(yx, yy);
}

// ---------------- pure gather-add aggregate over pre-scaled bf16 rows ----------------
// a_i = dinv_i * ( sum_e y'[src] + y'[i] ) with y' already dinv*activation-scaled.
// Edge list is row-padded to mult-of-8 with a zero sentinel row. p0/p1 are forced
// to SGPRs so the edge-index fetch becomes s_load_dwordx4 (SMEM pipe, runs ahead
// of vector gathers); per-edge address math is scalar; 8 (16 w/ unroll) gathers
// in flight per wave. RB = row stride in bytes of h.
template<int CPACK, int RB, int OS, bool OBF>
__global__ __launch_bounds__(256) void k_gather(
    const unsigned* __restrict__ h, void* __restrict__ aout,
    const int* __restrict__ rowptr, const unsigned* __restrict__ ew,
    const float* __restrict__ dinv) {
    int node = (blockIdx.x * 256 + threadIdx.x) >> 6;
    int lane = threadIdx.x & 63;
    if (node >= NNODES) return;
    int p0 = __builtin_amdgcn_readfirstlane(rowptr[node]);
    int p1 = __builtin_amdgcn_readfirstlane(rowptr[node + 1]);
    float di = dinv[node];
    bool act = lane < CPACK;
    unsigned l4 = (unsigned)(lane << 2);
    const char* __restrict__ hb = (const char*)h;
    float ax = 0.f, ay = 0.f;
    if (act) {
        unsigned hv = h[node * CPACK + lane];   // self term (already dinv-scaled)
        ax = unp_lo(hv); ay = unp_hi(hv);
    }
    const uint4* __restrict__ E4 = (const uint4*)(ew + p0);   // 16B-aligned (p0 mult of 8)
    int n8 = (p1 - p0) >> 3;
    #pragma unroll 2
    for (int q = 0; q < n8; ++q) {
        uint4 ea = E4[2 * q];
        uint4 eb = E4[2 * q + 1];
        if (act) {
            unsigned v0 = *(const unsigned*)(hb + (ea.x * (unsigned)RB + l4));
            unsigned v1 = *(const unsigned*)(hb + (ea.y * (unsigned)RB + l4));
            unsigned v2 = *(const unsigned*)(hb + (ea.z * (unsigned)RB + l4));
            unsigned v3 = *(const unsigned*)(hb + (ea.w * (unsigned)RB + l4));
            unsigned v4 = *(const unsigned*)(hb + (eb.x * (unsigned)RB + l4));
            unsigned v5 = *(const unsigned*)(hb + (eb.y * (unsigned)RB + l4));
            unsigned v6 = *(const unsigned*)(hb + (eb.z * (unsigned)RB + l4));
            unsigned v7 = *(const unsigned*)(hb + (eb.w * (unsigned)RB + l4));
            ax += unp_lo(v0); ay += unp_hi(v0);
            ax += unp_lo(v1); ay += unp_hi(v1);
            ax += unp_lo(v2); ay += unp_hi(v2);
            ax += unp_lo(v3); ay += unp_hi(v3);
            ax += unp_lo(v4); ay += unp_hi(v4);
            ax += unp_lo(v5); ay += unp_hi(v5);
            ax += unp_lo(v6); ay += unp_hi(v6);
            ax += unp_lo(v7); ay += unp_hi(v7);
        }
    }
    float ox = di * ax, oy = di * ay;
    if constexpr (OBF) {
        if (lane < OS)
            ((unsigned*)aout)[(size_t)node * OS + lane] = pack_bf16(ox, oy);
    } else {
        if (lane < (OS + 1) / 2)
            ((float2*)((float*)aout + (size_t)node * OS))[lane] = make_float2(ox, oy);
    }
}

// ---------------- CH-layer GEMM (512 thr, 4x4 tile; R14 hot loop) ----------------
__global__ __launch_bounds__(512) void k_gemm_ch(
    const unsigned* __restrict__ Ab, const float* __restrict__ W,
    const float* __restrict__ bias, unsigned* __restrict__ Zb,
    float* __restrict__ gsum, float* __restrict__ gsq) {
    __shared__ __align__(16) float wS[CH * CH];   // 40 KB
    __shared__ __align__(16) float aS[64 * CH];   // 25.6 KB
    __shared__ float sSum[CH], sSq[CH];
    int tid = threadIdx.x;
    for (int i = tid; i < CH; i += 512) { sSum[i] = 0.f; sSq[i] = 0.f; }
    for (int i = tid; i < CH * CH; i += 512) wS[i] = W[i];
    int row0 = blockIdx.x * 64;
    {
        const unsigned* As = Ab + (size_t)row0 * 50;
        int maxI = (NNODES - row0) * 50;   // >= 3200 except last block
        for (int i = tid; i < 64 * 50; i += 512) {
            unsigned v = (i < maxI) ? As[i] : 0u;
            ((float2*)aS)[i] = make_float2(unp_lo(v), unp_hi(v));
        }
    }
    __syncthreads();
    if (tid < 400) {
        int ct = tid % 25, rt = tid / 25;  // ct 0..24, rt 0..15
        int c0 = ct * 4, r0 = rt * 4;
        float acc[4][4] = {};
        for (int k = 0; k < CH; k += 4) {
            float4 w0 = *(const float4*)&wS[(k + 0) * CH + c0];
            float4 w1 = *(const float4*)&wS[(k + 1) * CH + c0];
            float4 w2 = *(const float4*)&wS[(k + 2) * CH + c0];
            float4 w3 = *(const float4*)&wS[(k + 3) * CH + c0];
            #pragma unroll
            for (int j = 0; j < 4; ++j) {
                float4 av = *(const float4*)&aS[(r0 + j) * CH + k];
                acc[j][0] += av.x * w0.x + av.y * w1.x + av.z * w2.x + av.w * w3.x;
                acc[j][1] += av.x * w0.y + av.y * w1.y + av.z * w2.y + av.w * w3.y;
                acc[j][2] += av.x * w0.z + av.y * w1.z + av.z * w2.z + av.w * w3.z;
                acc[j][3] += av.x * w0.w + av.y * w1.w + av.z * w2.w + av.w * w3.w;
            }
        }
        float4 bv = *(const float4*)&bias[c0];
        float cs0 = 0, cs1 = 0, cs2 = 0, cs3 = 0, cq0 = 0, cq1 = 0, cq2 = 0, cq3 = 0;
        #pragma unroll
        for (int j = 0; j < 4; ++j) {
            int r = row0 + r0 + j;
            if (r < NNODES) {
                float z0 = acc[j][0] + bv.x, z1 = acc[j][1] + bv.y;
                float z2 = acc[j][2] + bv.z, z3 = acc[j][3] + bv.w;
                *(uint2*)&Zb[(size_t)r * 50 + (c0 >> 1)] =
                    make_uint2(pack_bf16(z0, z1), pack_bf16(z2, z3));
                cs0 += z0; cs1 += z1; cs2 += z2; cs3 += z3;
                cq0 += z0 * z0; cq1 += z1 * z1; cq2 += z2 * z2; cq3 += z3 * z3;
            }
        }
        atomicAdd(&sSum[c0], cs0); atomicAdd(&sSum[c0 + 1], cs1);
        atomicAdd(&sSum[c0 + 2], cs2); atomicAdd(&sSum[c0 + 3], cs3);
        atomicAdd(&sSq[c0], cq0); atomicAdd(&sSq[c0 + 1], cq1);
        atomicAdd(&sSq[c0 + 2], cq2); atomicAdd(&sSq[c0 + 3], cq3);
    }
    __syncthreads();
    int sh = (blockIdx.x & (NSHARD - 1)) * SHSTRIDE;
    if (tid < CH) { atomicAdd(&gsum[sh + tid], sSum[tid]); atomicAdd(&gsq[sh + tid], sSq[tid]); }
}

// ---------------- layer-0 GEMM (512 thr, 4x4 tile, K=36, unroll-capped) ----------------
__global__ __launch_bounds__(512) void k_gemm0(
    const float* __restrict__ A, const float* __restrict__ W, const float* __restrict__ bias,
    unsigned* __restrict__ Zb, float* __restrict__ gsum, float* __restrict__ gsq) {
    constexpr int K = CIN0, KP = 36;
    __shared__ __align__(16) float wS[KP * CH];   // 14.4 KB
    __shared__ __align__(16) float aS[64 * KP];   // 9.2 KB
    __shared__ float sSum[CH], sSq[CH];
    int tid = threadIdx.x;
    for (int i = tid; i < CH; i += 512) { sSum[i] = 0.f; sSq[i] = 0.f; }
    for (int i = tid; i < KP * CH; i += 512) wS[i] = (i < K * CH) ? W[i] : 0.f;
    int row0 = blockIdx.x * 64;
    {
        const float* As = A + (size_t)row0 * KP;
        int maxI = (NNODES - row0) * KP;
        for (int i = tid; i < 64 * KP; i += 512) aS[i] = (i < maxI) ? As[i] : 0.f;
    }
    __syncthreads();
    if (tid < 400) {
        int ct = tid % 25, rt = tid / 25;  // ct 0..24, rt 0..15
        int c0 = ct * 4, r0 = rt * 4;
        float acc[4][4] = {};
        #pragma unroll 1
        for (int k = 0; k < KP; k += 4) {
            float4 w0 = *(const float4*)&wS[(k + 0) * CH + c0];
            float4 w1 = *(const float4*)&wS[(k + 1) * CH + c0];
            float4 w2 = *(const float4*)&wS[(k + 2) * CH + c0];
            float4 w3 = *(const float4*)&wS[(k + 3) * CH + c0];
            #pragma unroll
            for (int j = 0; j < 4; ++j) {
                float4 av = *(const float4*)&aS[(r0 + j) * KP + k];
                acc[j][0] += av.x * w0.x + av.y * w1.x + av.z * w2.x + av.w * w3.x;
                acc[j][1] += av.x * w0.y + av.y * w1.y + av.z * w2.y + av.w * w3.y;
                acc[j][2] += av.x * w0.z + av.y * w1.z + av.z * w2.z + av.w * w3.z;
                acc[j][3] += av.x * w0.w + av.y * w1.w + av.z * w2.w + av.w * w3.w;
            }
        }
        float4 bv = *(const float4*)&bias[c0];
        float cs0 = 0, cs1 = 0, cs2 = 0, cs3 = 0, cq0 = 0, cq1 = 0, cq2 = 0, cq3 = 0;
        #pragma unroll
        for (int j = 0; j < 4; ++j) {
            int r = row0 + r0 + j;
            if (r < NNODES) {
                float z0 = acc[j][0] + bv.x, z1 = acc[j][1] + bv.y;
                float z2 = acc[j][2] + bv.z, z3 = acc[j][3] + bv.w;
                *(uint2*)&Zb[(size_t)r * 50 + (c0 >> 1)] =
                    make_uint2(pack_bf16(z0, z1), pack_bf16(z2, z3));
                cs0 += z0; cs1 += z1; cs2 += z2; cs3 += z3;
                cq0 += z0 * z0; cq1 += z1 * z1; cq2 += z2 * z2; cq3 += z3 * z3;
            }
        }
        atomicAdd(&sSum[c0], cs0); atomicAdd(&sSum[c0 + 1], cs1);
        atomicAdd(&sSum[c0 + 2], cs2); atomicAdd(&sSum[c0 + 3], cs3);
        atomicAdd(&sSq[c0], cq0); atomicAdd(&sSq[c0 + 1], cq1);
        atomicAdd(&sSq[c0 + 2], cq2); atomicAdd(&sSq[c0 + 3], cq3);
    }
    __syncthreads();
    int sh = (blockIdx.x & (NSHARD - 1)) * SHSTRIDE;
    if (tid < CH) { atomicAdd(&gsum[sh + tid], sSum[tid]); atomicAdd(&gsq[sh + tid], sSq[tid]); }
}

// ---------------- global_add_pool of BN(z) from bf16 Z; 4 row-chunks per graph ----------------
__global__ void k_pool(const unsigned* __restrict__ Zl, const int* __restrict__ batch,
                       const float* __restrict__ gsum, const float* __restrict__ gsq,
                       const float* __restrict__ gamma, const float* __restrict__ beta,
                       float* __restrict__ g) {
    int gid = blockIdx.x;
    int part = blockIdx.y;
    int lo = 0, hi = NNODES;
    while (lo < hi) { int mid = (lo + hi) >> 1; if (batch[mid] < gid) lo = mid + 1; else hi = mid; }
    int start = lo;
    hi = NNODES;
    while (lo < hi) { int mid = (lo + hi) >> 1; if (batch[mid] < gid + 1) lo = mid + 1; else hi = mid; }
    int end = lo;
    int len = end - start;
    int cb = (len + 3) >> 2;
    int s = start + part * cb;
    int e = s + cb; if (e > end) e = end;
    if (s >= e) return;
    int t = threadIdx.x;
    if (t >= 50) return;
    float su = 0.f, sv = 0.f, qu = 0.f, qv = 0.f;
    #pragma unroll
    for (int sh = 0; sh < NSHARD; ++sh) {
        float2 s2 = ((const float2*)(gsum + sh * SHSTRIDE))[t];
        float2 q2 = ((const float2*)(gsq + sh * SHSTRIDE))[t];
        su += s2.x; sv += s2.y; qu += q2.x; qv += q2.y;
    }
    constexpr float invN = 1.f / NNODES;
    float2 g2 = ((const float2*)gamma)[t];
    float2 b2 = ((const float2*)beta)[t];
    float mx = su * invN, my = sv * invN;
    float vx = qu * invN - mx * mx, vy = qv * invN - my * my;
    float scx = g2.x * rsqrtf(vx + BN_EPS), shx = b2.x - mx * scx;
    float scy = g2.y * rsqrtf(vy + BN_EPS), shy = b2.y - my * scy;
    float sx = 0.f, sy = 0.f;
    for (int r = s; r < e; ++r) {
        unsigned v = Zl[(size_t)r * 50 + t];
        sx += unp_lo(v); sy += unp_hi(v);
    }
    float n = (float)(e - s);
    atomicAdd(&g[gid * CH + 2 * t], sx * scx + n * shx);
    atomicAdd(&g[gid * CH + 2 * t + 1], sy * scy + n * shy);
}

// ---------------- out = leakyrelu(g @ Wout + bout, 0.1) ----------------
__global__ __launch_bounds__(256) void k_out(const float* __restrict__ g,
                                             const float* __restrict__ Wout,
                                             const float* __restrict__ bout,
                                             float* __restrict__ out) {
    __shared__ float gS[CH];
    int gid = blockIdx.x, tid = threadIdx.x;
    if (tid < CH) gS[tid] = g[gid * CH + tid];
    __syncthreads();
    if (tid >= 200) return;
    float acc = bout[tid];
    for (int k = 0; k < CH; ++k) acc += gS[k] * Wout[k * 200 + tid];
    out[gid * 200 + tid] = acc > 0.f ? acc : 0.1f * acc;
}

extern "C" void kernel_launch(void* const* d_in, const int* in_sizes, int n_in,
                              void* d_out, int out_size, void* d_ws, size_t ws_size,
                              hipStream_t stream) {
    const float* x = (const float*)d_in[0];
    const int* ei = (const int*)d_in[1];
    const int* batch = (const int*)d_in[2];
    const float* W0 = (const float*)d_in[3];
    const float* Wrest = (const float*)d_in[4];
    const float* b = (const float*)d_in[5];
    const float* gamma = (const float*)d_in[6];
    const float* beta = (const float*)d_in[7];
    const float* Wout = (const float*)d_in[8];
    const float* bout = (const float*)d_in[9];
    float* out = (float*)d_out;
    const int* srcA = ei;
    const int* dstA = ei + NEDGES;

    char* wsb = (char*)d_ws;
    size_t off = 0;
    auto alloc = [&](size_t elems) -> void* {
        void* p = (void*)(wsb + off);
        off += ((elems + 7) & ~(size_t)7) * 4;
        return p;
    };
    int* cnt = (int*)alloc(NNODES);
    int* rowptr = (int*)alloc(NNODES + 1);
    int* cursor = (int*)alloc(NNODES);
    float* dinv = (float*)alloc(NNODES);
    int* scanBlk = (int*)alloc(64);
    int* scanOff = (int*)alloc(64);
    float* stats = (float*)alloc(NSHARD * SHSTRIDE);  // per shard: [l*128]=sum, [512+l*128]=sq
    unsigned* ew = (unsigned*)alloc(PADE);             // src node indices, padded CSR
    unsigned* xb = (unsigned*)alloc((size_t)(NNODES + 1) * 17);
    // union: A0 (fp32, N*36 words, layer-0 only) / Y (bf16, (N+1)*50 words, layers 1-3)
    float* A0 = (float*)alloc((size_t)(NNODES + 1) * 50);
    unsigned* Y = (unsigned*)A0;
    unsigned* Abf = (unsigned*)alloc((size_t)NNODES * 50);
    unsigned* Zb = (unsigned*)alloc((size_t)NNODES * 50);
    float* gbuf = (float*)alloc((size_t)NGRAPH * CH);
    (void)ws_size; (void)n_in; (void)in_sizes; (void)out_size;

    hipLaunchKernelGGL(k_init, dim3((PADE + 255) / 256), dim3(256), 0, stream,
                       cnt, stats, gbuf, ew);
    hipLaunchKernelGGL(k_hist, dim3((NEDGES + 255) / 256), dim3(256), 0, stream, dstA, cnt);
    hipLaunchKernelGGL(k_scan1, dim3(SCAN_BLOCKS), dim3(SCAN_TPB), 0, stream, cnt, rowptr, scanBlk, dinv);
    hipLaunchKernelGGL(k_scan2, dim3(1), dim3(64), 0, stream, scanBlk, scanOff, rowptr);
    hipLaunchKernelGGL(k_scan3, dim3(SCAN_BLOCKS), dim3(SCAN_TPB), 0, stream, rowptr, cursor, scanOff);
    hipLaunchKernelGGL(k_packx, dim3(((NNODES + 1) * 17 + 255) / 256), dim3(256), 0, stream,
                       x, xb, dinv);
    hipLaunchKernelGGL(k_scatter, dim3((NEDGES + 255) / 256), dim3(256), 0, stream,
                       srcA, dstA, cursor, ew);

    // ---- layer 0 ----
    hipLaunchKernelGGL((k_gather<17, 68, 36, false>), dim3(12500), dim3(256), 0, stream,
                       xb, A0, rowptr, ew, dinv);
    hipLaunchKernelGGL(k_gemm0, dim3((NNODES + 63) / 64), dim3(512), 0, stream,
                       A0, W0, b, Zb, stats + 0 * 128, stats + 512 + 0 * 128);
    // ---- layers 1..3 ----
    for (int l = 1; l < 4; ++l) {
        float* ps = stats + (l - 1) * 128;
        float* pq = stats + 512 + (l - 1) * 128;
        hipLaunchKernelGGL(k_bnact, dim3(((NNODES + 1) * 50 + 255) / 256), dim3(256), 0, stream,
                           Zb, Y, ps, pq, gamma + (l - 1) * CH, beta + (l - 1) * CH, dinv);
        hipLaunchKernelGGL((k_gather<50, 200, 50, true>), dim3(12500), dim3(256), 0, stream,
                           Y, Abf, rowptr, ew, dinv);
        hipLaunchKernelGGL(k_gemm_ch, dim3((NNODES + 63) / 64), dim3(512), 0, stream,
                           Abf, Wrest + (l - 1) * 10000, b + l * CH, Zb,
                           stats + l * 128, stats + 512 + l * 128);
    }
    hipLaunchKernelGGL(k_pool, dim3(NGRAPH, 4), dim3(64), 0, stream, Zb, batch,
                       stats + 3 * 128, stats + 512 + 3 * 128, gamma + 3 * CH, beta + 3 * CH, gbuf);
    hipLaunchKernelGGL(k_out, dim3(NGRAPH), dim3(256), 0, stream, gbuf, Wout, bout, out);
}

// Round 3
// 518.518 us; speedup vs baseline: 1.0929x; 1.0522x over previous
//
#include <hip/hip_runtime.h>

#define NNODES 50000
#define NEDGES 800000
#define NGRAPH 500
#define CH 100
#define CIN0 33
#define BN_EPS 1e-5f
#define NSHARD 8
#define SHSTRIDE 1024   // floats per shard: [4 layers][sum128|sq128]
#define NBUK 196        // = ceil(NNODES/256); bucket b covers dst nodes [b*256, b*256+256)
#define BEPW 2048       // edges per workgroup in k_bin

#define SCAN_TPB 256
#define SCAN_IPT 4
#define SCAN_TILE (SCAN_TPB * SCAN_IPT)
#define SCAN_BLOCKS ((NNODES + SCAN_TILE - 1) / SCAN_TILE)

// pack two fp32 into (bf16(x) | bf16(y)<<16), round-to-nearest-even
__device__ inline unsigned pack_bf16(float x, float y) {
    unsigned xb = __float_as_uint(x);
    unsigned yb = __float_as_uint(y);
    xb += 0x7FFF + ((xb >> 16) & 1);
    yb += 0x7FFF + ((yb >> 16) & 1);
    return (xb >> 16) | (yb & 0xFFFF0000u);
}
__device__ inline float unp_lo(unsigned v) { return __uint_as_float(v << 16); }
__device__ inline float unp_hi(unsigned v) { return __uint_as_float(v & 0xFFFF0000u); }

// ---------------- init: zero counters + BN stat shards + pool accumulator ----------------
__global__ void k_init(int* __restrict__ cnt, float* __restrict__ stats,
                       float* __restrict__ gbuf) {
    int i = blockIdx.x * blockDim.x + threadIdx.x;
    if (i < NNODES) cnt[i] = 0;
    if (i < NGRAPH * CH) gbuf[i] = 0.f;   // NGRAPH*CH == NNODES
    if (i < NSHARD * SHSTRIDE) stats[i] = 0.f;
}

// ---------------- in-degree histogram over dst ----------------
__global__ void k_hist(const int* __restrict__ dst, int* __restrict__ cnt) {
    int e = blockIdx.x * blockDim.x + threadIdx.x;
    if (e < NEDGES) atomicAdd(&cnt[dst[e]], 1);
}

// ---------------- pack dinv[r]*x into bf16 rows of 17 uints (+1 zero sentinel row) ----------------
__global__ void k_packx(const float* __restrict__ x, unsigned* __restrict__ xb,
                        const float* __restrict__ dinv) {
    int i = blockIdx.x * blockDim.x + threadIdx.x;
    if (i >= (NNODES + 1) * 17) return;
    int r = i / 17, s = i - r * 17;
    if (r >= NNODES) { xb[i] = 0u; return; }
    float di = dinv[r];
    float a = di * x[r * CIN0 + 2 * s];
    float b = (2 * s + 1 < CIN0) ? di * x[r * CIN0 + 2 * s + 1] : 0.f;
    xb[i] = pack_bf16(a, b);
}

// ---------------- exclusive scan of padded counts -> rowptr; dinv; per-bucket edge counts ----------------
// SCAN_TILE=1024 nodes/block = exactly 4 buckets of 256 nodes -> bucket sums need no global atomics.
__global__ void k_scan1(const int* __restrict__ cnt, int* __restrict__ rowptr,
                        int* __restrict__ blkSums, float* __restrict__ dinv,
                        int* __restrict__ bcnt) {
    __shared__ int ts[SCAN_TPB];
    __shared__ int bsum[4];
    int tid = threadIdx.x;
    if (tid < 4) bsum[tid] = 0;
    int base = blockIdx.x * SCAN_TILE + tid * SCAN_IPT;
    int v[SCAN_IPT];
    int s = 0, cact = 0;
    #pragma unroll
    for (int j = 0; j < SCAN_IPT; ++j) {
        int i = base + j;
        int c = (i < NNODES) ? cnt[i] : 0;
        if (i < NNODES) dinv[i] = rsqrtf((float)(c + 1));
        v[j] = (c + 7) & ~7;   // pad each row to multiple of 8 edges
        s += v[j];
        cact += c;
    }
    ts[tid] = s;
    __syncthreads();
    atomicAdd(&bsum[(tid * SCAN_IPT) >> 8], cact);   // 4 nodes always in one bucket
    for (int off = 1; off < SCAN_TPB; off <<= 1) {
        int add = (tid >= off) ? ts[tid - off] : 0;
        __syncthreads();
        ts[tid] += add;
        __syncthreads();
    }
    int run = ts[tid] - s;  // exclusive prefix within block
    #pragma unroll
    for (int j = 0; j < SCAN_IPT; ++j) {
        int i = base + j;
        if (i < NNODES) rowptr[i] = run;
        run += v[j];
    }
    if (tid == SCAN_TPB - 1) blkSums[blockIdx.x] = ts[tid];
    if (tid < 4) {
        int b = blockIdx.x * 4 + tid;
        if (b < NBUK) bcnt[b] = bsum[tid];
    }
}

__global__ void k_scan2(const int* __restrict__ blkSums, int* __restrict__ blkOff,
                        int* __restrict__ rowptr) {
    if (threadIdx.x == 0) {
        int run = 0;
        for (int i = 0; i < SCAN_BLOCKS; ++i) { blkOff[i] = run; run += blkSums[i]; }
        rowptr[NNODES] = run;   // total padded edges
    }
}

__global__ void k_scan3(int* __restrict__ rowptr, const int* __restrict__ blkOff) {
    int off = blkOff[blockIdx.x];
    int base = blockIdx.x * SCAN_TILE + threadIdx.x * SCAN_IPT;
    #pragma unroll
    for (int j = 0; j < SCAN_IPT; ++j) {
        int i = base + j;
        if (i < NNODES) rowptr[i] += off;
    }
}

// ---------------- exclusive scan of bucket counts -> staging bases (+ working cursors) ----------------
__global__ void k_bscan(const int* __restrict__ bcnt, int* __restrict__ bbase,
                        int* __restrict__ gbkcur) {
    __shared__ int ts[256];
    int t = threadIdx.x;
    int v = (t < NBUK) ? bcnt[t] : 0;
    ts[t] = v;
    __syncthreads();
    for (int off = 1; off < 256; off <<= 1) {
        int a = (t >= off) ? ts[t - off] : 0;
        __syncthreads();
        ts[t] += a;
        __syncthreads();
    }
    int excl = ts[t] - v;
    if (t < NBUK) { bbase[t] = excl; gbkcur[t] = excl; }
    if (t == NBUK - 1) bbase[NBUK] = ts[t];
}

// ---------------- phase A: bin edges by dst-bucket into bucket-major staging (coalesced-ish writes) ----------------
__global__ __launch_bounds__(256) void k_bin(const int* __restrict__ src,
                                             const int* __restrict__ dst,
                                             int* __restrict__ gbkcur,
                                             uint2* __restrict__ ebuf) {
    __shared__ int hist[256], ofs[256], lcnt[256], bbaseL[256];
    __shared__ int totS;
    __shared__ uint2 stage[BEPW];   // 16 KB
    int tid = threadIdx.x;
    hist[tid] = 0; lcnt[tid] = 0;
    __syncthreads();
    int e0 = blockIdx.x * BEPW;
    unsigned sv[8]; int dv[8]; bool ok[8];
    #pragma unroll
    for (int j = 0; j < 8; ++j) {
        int e = e0 + j * 256 + tid;
        ok[j] = e < NEDGES;
        sv[j] = ok[j] ? (unsigned)src[e] : 0u;
        dv[j] = ok[j] ? dst[e] : 0;
        if (ok[j]) atomicAdd(&hist[dv[j] >> 8], 1);
    }
    __syncthreads();
    int v = hist[tid];
    ofs[tid] = v;
    __syncthreads();
    for (int off = 1; off < 256; off <<= 1) {
        int a = (tid >= off) ? ofs[tid - off] : 0;
        __syncthreads();
        ofs[tid] += a;
        __syncthreads();
    }
    if (tid == 255) totS = ofs[255];
    int excl = ofs[tid] - v;
    __syncthreads();
    ofs[tid] = excl;
    if (tid < NBUK && v > 0) bbaseL[tid] = atomicAdd(&gbkcur[tid], v);
    __syncthreads();
    #pragma unroll
    for (int j = 0; j < 8; ++j) {
        if (ok[j]) {
            int b = dv[j] >> 8;
            int idx = atomicAdd(&lcnt[b], 1);
            stage[ofs[b] + idx] = make_uint2(sv[j], (unsigned)dv[j]);
        }
    }
    __syncthreads();
    int tot = totS;
    #pragma unroll
    for (int j = 0; j < 8; ++j) {
        int slot = j * 256 + tid;
        if (slot < tot) {
            uint2 p = stage[slot];
            int b = (int)(p.y >> 8);
            ebuf[bbaseL[b] + (slot - ofs[b])] = p;
        }
    }
}

// ---------------- phase B: place edges into padded CSR; LDS cursors; dense L2-local writes; pad fill ----------------
__global__ __launch_bounds__(256) void k_place(const uint2* __restrict__ ebuf,
                                               const int* __restrict__ bbase,
                                               const int* __restrict__ rowptr,
                                               unsigned* __restrict__ ew) {
    __shared__ int lcur[256];
    int b = blockIdx.x, t = threadIdx.x;
    int lo = b * 256;
    int n = NNODES - lo; if (n > 256) n = 256;
    if (t < n) lcur[t] = rowptr[lo + t];
    __syncthreads();
    int e0 = bbase[b], e1 = bbase[b + 1];
    for (int e = e0 + t; e < e1; e += 256) {
        uint2 p = ebuf[e];
        int pos = atomicAdd(&lcur[p.y & 255], 1);
        ew[pos] = p.x;
    }
    __syncthreads();
    if (t < n) {
        int end = rowptr[lo + t + 1];
        for (int q = lcur[t]; q < end; ++q) ew[q] = NNODES;   // sentinel pads
    }
}

// ---------------- apply y = dinv * relu(BN(z)) in bf16, one streaming pass ----------------
__global__ __launch_bounds__(256) void k_bnact(
    const unsigned* __restrict__ Zb, unsigned* __restrict__ Y,
    const float* __restrict__ gsum, const float* __restrict__ gsq,
    const float* __restrict__ gamma, const float* __restrict__ beta,
    const float* __restrict__ dinv) {
    int i = blockIdx.x * blockDim.x + threadIdx.x;
    if (i >= (NNODES + 1) * 50) return;
    int node = i / 50, c = i - node * 50;
    if (node >= NNODES) { Y[i] = 0u; return; }   // zero sentinel row
    float sx = 0.f, sy = 0.f, qx = 0.f, qy = 0.f;
    #pragma unroll
    for (int sh = 0; sh < NSHARD; ++sh) {
        float2 s2 = ((const float2*)(gsum + sh * SHSTRIDE))[c];
        float2 q2 = ((const float2*)(gsq + sh * SHSTRIDE))[c];
        sx += s2.x; sy += s2.y; qx += q2.x; qy += q2.y;
    }
    constexpr float invN = 1.f / NNODES;
    float2 g2 = ((const float2*)gamma)[c];
    float2 b2 = ((const float2*)beta)[c];
    float mx = sx * invN, my = sy * invN;
    float vx = qx * invN - mx * mx, vy = qy * invN - my * my;
    float scx = g2.x * rsqrtf(vx + BN_EPS), shx = b2.x - mx * scx;
    float scy = g2.y * rsqrtf(vy + BN_EPS), shy = b2.y - my * scy;
    float di = dinv[node];
    unsigned v = Zb[i];
    float yx = fmaxf(unp_lo(v) * scx + shx, 0.f) * di;
    float yy = fmaxf(unp_hi(v) * scy + shy, 0.f) * di;
    Y[i] = pack_bf16(yx, yy);
}

// ---------------- pure gather-add aggregate over pre-scaled bf16 rows ----------------
template<int CPACK, int RB, int OS, bool OBF>
__global__ __launch_bounds__(256) void k_gather(
    const unsigned* __restrict__ h, void* __restrict__ aout,
    const int* __restrict__ rowptr, const unsigned* __restrict__ ew,
    const float* __restrict__ dinv) {
    int node = (blockIdx.x * 256 + threadIdx.x) >> 6;
    int lane = threadIdx.x & 63;
    if (node >= NNODES) return;
    int p0 = __builtin_amdgcn_readfirstlane(rowptr[node]);
    int p1 = __builtin_amdgcn_readfirstlane(rowptr[node + 1]);
    float di = dinv[node];
    bool act = lane < CPACK;
    unsigned l4 = (unsigned)(lane << 2);
    const char* __restrict__ hb = (const char*)h;
    float ax = 0.f, ay = 0.f;
    if (act) {
        unsigned hv = h[node * CPACK + lane];   // self term (already dinv-scaled)
        ax = unp_lo(hv); ay = unp_hi(hv);
    }
    const uint4* __restrict__ E4 = (const uint4*)(ew + p0);   // 16B-aligned (p0 mult of 8)
    int n8 = (p1 - p0) >> 3;
    #pragma unroll 2
    for (int q = 0; q < n8; ++q) {
        uint4 ea = E4[2 * q];
        uint4 eb = E4[2 * q + 1];
        if (act) {
            unsigned v0 = *(const unsigned*)(hb + (ea.x * (unsigned)RB + l4));
            unsigned v1 = *(const unsigned*)(hb + (ea.y * (unsigned)RB + l4));
            unsigned v2 = *(const unsigned*)(hb + (ea.z * (unsigned)RB + l4));
            unsigned v3 = *(const unsigned*)(hb + (ea.w * (unsigned)RB + l4));
            unsigned v4 = *(const unsigned*)(hb + (eb.x * (unsigned)RB + l4));
            unsigned v5 = *(const unsigned*)(hb + (eb.y * (unsigned)RB + l4));
            unsigned v6 = *(const unsigned*)(hb + (eb.z * (unsigned)RB + l4));
            unsigned v7 = *(const unsigned*)(hb + (eb.w * (unsigned)RB + l4));
            ax += unp_lo(v0); ay += unp_hi(v0);
            ax += unp_lo(v1); ay += unp_hi(v1);
            ax += unp_lo(v2); ay += unp_hi(v2);
            ax += unp_lo(v3); ay += unp_hi(v3);
            ax += unp_lo(v4); ay += unp_hi(v4);
            ax += unp_lo(v5); ay += unp_hi(v5);
            ax += unp_lo(v6); ay += unp_hi(v6);
            ax += unp_lo(v7); ay += unp_hi(v7);
        }
    }
    float ox = di * ax, oy = di * ay;
    if constexpr (OBF) {
        if (lane < OS)
            ((unsigned*)aout)[(size_t)node * OS + lane] = pack_bf16(ox, oy);
    } else {
        if (lane < (OS + 1) / 2)
            ((float2*)((float*)aout + (size_t)node * OS))[lane] = make_float2(ox, oy);
    }
}

// ---------------- CH-layer GEMM (512 thr, 4x4 tile; R14 hot loop) ----------------
__global__ __launch_bounds__(512) void k_gemm_ch(
    const unsigned* __restrict__ Ab, const float* __restrict__ W,
    const float* __restrict__ bias, unsigned* __restrict__ Zb,
    float* __restrict__ gsum, float* __restrict__ gsq) {
    __shared__ __align__(16) float wS[CH * CH];   // 40 KB
    __shared__ __align__(16) float aS[64 * CH];   // 25.6 KB
    __shared__ float sSum[CH], sSq[CH];
    int tid = threadIdx.x;
    for (int i = tid; i < CH; i += 512) { sSum[i] = 0.f; sSq[i] = 0.f; }
    for (int i = tid; i < CH * CH; i += 512) wS[i] = W[i];
    int row0 = blockIdx.x * 64;
    {
        const unsigned* As = Ab + (size_t)row0 * 50;
        int maxI = (NNODES - row0) * 50;   // >= 3200 except last block
        for (int i = tid; i < 64 * 50; i += 512) {
            unsigned v = (i < maxI) ? As[i] : 0u;
            ((float2*)aS)[i] = make_float2(unp_lo(v), unp_hi(v));
        }
    }
    __syncthreads();
    if (tid < 400) {
        int ct = tid % 25, rt = tid / 25;  // ct 0..24, rt 0..15
        int c0 = ct * 4, r0 = rt * 4;
        float acc[4][4] = {};
        for (int k = 0; k < CH; k += 4) {
            float4 w0 = *(const float4*)&wS[(k + 0) * CH + c0];
            float4 w1 = *(const float4*)&wS[(k + 1) * CH + c0];
            float4 w2 = *(const float4*)&wS[(k + 2) * CH + c0];
            float4 w3 = *(const float4*)&wS[(k + 3) * CH + c0];
            #pragma unroll
            for (int j = 0; j < 4; ++j) {
                float4 av = *(const float4*)&aS[(r0 + j) * CH + k];
                acc[j][0] += av.x * w0.x + av.y * w1.x + av.z * w2.x + av.w * w3.x;
                acc[j][1] += av.x * w0.y + av.y * w1.y + av.z * w2.y + av.w * w3.y;
                acc[j][2] += av.x * w0.z + av.y * w1.z + av.z * w2.z + av.w * w3.z;
                acc[j][3] += av.x * w0.w + av.y * w1.w + av.z * w2.w + av.w * w3.w;
            }
        }
        float4 bv = *(const float4*)&bias[c0];
        float cs0 = 0, cs1 = 0, cs2 = 0, cs3 = 0, cq0 = 0, cq1 = 0, cq2 = 0, cq3 = 0;
        #pragma unroll
        for (int j = 0; j < 4; ++j) {
            int r = row0 + r0 + j;
            if (r < NNODES) {
                float z0 = acc[j][0] + bv.x, z1 = acc[j][1] + bv.y;
                float z2 = acc[j][2] + bv.z, z3 = acc[j][3] + bv.w;
                *(uint2*)&Zb[(size_t)r * 50 + (c0 >> 1)] =
                    make_uint2(pack_bf16(z0, z1), pack_bf16(z2, z3));
                cs0 += z0; cs1 += z1; cs2 += z2; cs3 += z3;
                cq0 += z0 * z0; cq1 += z1 * z1; cq2 += z2 * z2; cq3 += z3 * z3;
            }
        }
        atomicAdd(&sSum[c0], cs0); atomicAdd(&sSum[c0 + 1], cs1);
        atomicAdd(&sSum[c0 + 2], cs2); atomicAdd(&sSum[c0 + 3], cs3);
        atomicAdd(&sSq[c0], cq0); atomicAdd(&sSq[c0 + 1], cq1);
        atomicAdd(&sSq[c0 + 2], cq2); atomicAdd(&sSq[c0 + 3], cq3);
    }
    __syncthreads();
    int sh = (blockIdx.x & (NSHARD - 1)) * SHSTRIDE;
    if (tid < CH) { atomicAdd(&gsum[sh + tid], sSum[tid]); atomicAdd(&gsq[sh + tid], sSq[tid]); }
}

// ---------------- layer-0 GEMM (512 thr, 4x4 tile, K=36, unroll-capped) ----------------
__global__ __launch_bounds__(512) void k_gemm0(
    const float* __restrict__ A, const float* __restrict__ W, const float* __restrict__ bias,
    unsigned* __restrict__ Zb, float* __restrict__ gsum, float* __restrict__ gsq) {
    constexpr int K = CIN0, KP = 36;
    __shared__ __align__(16) float wS[KP * CH];   // 14.4 KB
    __shared__ __align__(16) float aS[64 * KP];   // 9.2 KB
    __shared__ float sSum[CH], sSq[CH];
    int tid = threadIdx.x;
    for (int i = tid; i < CH; i += 512) { sSum[i] = 0.f; sSq[i] = 0.f; }
    for (int i = tid; i < KP * CH; i += 512) wS[i] = (i < K * CH) ? W[i] : 0.f;
    int row0 = blockIdx.x * 64;
    {
        const float* As = A + (size_t)row0 * KP;
        int maxI = (NNODES - row0) * KP;
        for (int i = tid; i < 64 * KP; i += 512) aS[i] = (i < maxI) ? As[i] : 0.f;
    }
    __syncthreads();
    if (tid < 400) {
        int ct = tid % 25, rt = tid / 25;  // ct 0..24, rt 0..15
        int c0 = ct * 4, r0 = rt * 4;
        float acc[4][4] = {};
        #pragma unroll 1
        for (int k = 0; k < KP; k += 4) {
            float4 w0 = *(const float4*)&wS[(k + 0) * CH + c0];
            float4 w1 = *(const float4*)&wS[(k + 1) * CH + c0];
            float4 w2 = *(const float4*)&wS[(k + 2) * CH + c0];
            float4 w3 = *(const float4*)&wS[(k + 3) * CH + c0];
            #pragma unroll
            for (int j = 0; j < 4; ++j) {
                float4 av = *(const float4*)&aS[(r0 + j) * KP + k];
                acc[j][0] += av.x * w0.x + av.y * w1.x + av.z * w2.x + av.w * w3.x;
                acc[j][1] += av.x * w0.y + av.y * w1.y + av.z * w2.y + av.w * w3.y;
                acc[j][2] += av.x * w0.z + av.y * w1.z + av.z * w2.z + av.w * w3.z;
                acc[j][3] += av.x * w0.w + av.y * w1.w + av.z * w2.w + av.w * w3.w;
            }
        }
        float4 bv = *(const float4*)&bias[c0];
        float cs0 = 0, cs1 = 0, cs2 = 0, cs3 = 0, cq0 = 0, cq1 = 0, cq2 = 0, cq3 = 0;
        #pragma unroll
        for (int j = 0; j < 4; ++j) {
            int r = row0 + r0 + j;
            if (r < NNODES) {
                float z0 = acc[j][0] + bv.x, z1 = acc[j][1] + bv.y;
                float z2 = acc[j][2] + bv.z, z3 = acc[j][3] + bv.w;
                *(uint2*)&Zb[(size_t)r * 50 + (c0 >> 1)] =
                    make_uint2(pack_bf16(z0, z1), pack_bf16(z2, z3));
                cs0 += z0; cs1 += z1; cs2 += z2; cs3 += z3;
                cq0 += z0 * z0; cq1 += z1 * z1; cq2 += z2 * z2; cq3 += z3 * z3;
            }
        }
        atomicAdd(&sSum[c0], cs0); atomicAdd(&sSum[c0 + 1], cs1);
        atomicAdd(&sSum[c0 + 2], cs2); atomicAdd(&sSum[c0 + 3], cs3);
        atomicAdd(&sSq[c0], cq0); atomicAdd(&sSq[c0 + 1], cq1);
        atomicAdd(&sSq[c0 + 2], cq2); atomicAdd(&sSq[c0 + 3], cq3);
    }
    __syncthreads();
    int sh = (blockIdx.x & (NSHARD - 1)) * SHSTRIDE;
    if (tid < CH) { atomicAdd(&gsum[sh + tid], sSum[tid]); atomicAdd(&gsq[sh + tid], sSq[tid]); }
}

// ---------------- global_add_pool of BN(z) from bf16 Z; 4 row-chunks per graph ----------------
__global__ void k_pool(const unsigned* __restrict__ Zl, const int* __restrict__ batch,
                       const float* __restrict__ gsum, const float* __restrict__ gsq,
                       const float* __restrict__ gamma, const float* __restrict__ beta,
                       float* __restrict__ g) {
    int gid = blockIdx.x;
    int part = blockIdx.y;
    int lo = 0, hi = NNODES;
    while (lo < hi) { int mid = (lo + hi) >> 1; if (batch[mid] < gid) lo = mid + 1; else hi = mid; }
    int start = lo;
    hi = NNODES;
    while (lo < hi) { int mid = (lo + hi) >> 1; if (batch[mid] < gid + 1) lo = mid + 1; else hi = mid; }
    int end = lo;
    int len = end - start;
    int cb = (len + 3) >> 2;
    int s = start + part * cb;
    int e = s + cb; if (e > end) e = end;
    if (s >= e) return;
    int t = threadIdx.x;
    if (t >= 50) return;
    float su = 0.f, sv = 0.f, qu = 0.f, qv = 0.f;
    #pragma unroll
    for (int sh = 0; sh < NSHARD; ++sh) {
        float2 s2 = ((const float2*)(gsum + sh * SHSTRIDE))[t];
        float2 q2 = ((const float2*)(gsq + sh * SHSTRIDE))[t];
        su += s2.x; sv += s2.y; qu += q2.x; qv += q2.y;
    }
    constexpr float invN = 1.f / NNODES;
    float2 g2 = ((const float2*)gamma)[t];
    float2 b2 = ((const float2*)beta)[t];
    float mx = su * invN, my = sv * invN;
    float vx = qu * invN - mx * mx, vy = qv * invN - my * my;
    float scx = g2.x * rsqrtf(vx + BN_EPS), shx = b2.x - mx * scx;
    float scy = g2.y * rsqrtf(vy + BN_EPS), shy = b2.y - my * scy;
    float sx = 0.f, sy = 0.f;
    for (int r = s; r < e; ++r) {
        unsigned v = Zl[(size_t)r * 50 + t];
        sx += unp_lo(v); sy += unp_hi(v);
    }
    float n = (float)(e - s);
    atomicAdd(&g[gid * CH + 2 * t], sx * scx + n * shx);
    atomicAdd(&g[gid * CH + 2 * t + 1], sy * scy + n * shy);
}

// ---------------- out = leakyrelu(g @ Wout + bout, 0.1) ----------------
__global__ __launch_bounds__(256) void k_out(const float* __restrict__ g,
                                             const float* __restrict__ Wout,
                                             const float* __restrict__ bout,
                                             float* __restrict__ out) {
    __shared__ float gS[CH];
    int gid = blockIdx.x, tid = threadIdx.x;
    if (tid < CH) gS[tid] = g[gid * CH + tid];
    __syncthreads();
    if (tid >= 200) return;
    float acc = bout[tid];
    for (int k = 0; k < CH; ++k) acc += gS[k] * Wout[k * 200 + tid];
    out[gid * 200 + tid] = acc > 0.f ? acc : 0.1f * acc;
}

extern "C" void kernel_launch(void* const* d_in, const int* in_sizes, int n_in,
                              void* d_out, int out_size, void* d_ws, size_t ws_size,
                              hipStream_t stream) {
    const float* x = (const float*)d_in[0];
    const int* ei = (const int*)d_in[1];
    const int* batch = (const int*)d_in[2];
    const float* W0 = (const float*)d_in[3];
    const float* Wrest = (const float*)d_in[4];
    const float* b = (const float*)d_in[5];
    const float* gamma = (const float*)d_in[6];
    const float* beta = (const float*)d_in[7];
    const float* Wout = (const float*)d_in[8];
    const float* bout = (const float*)d_in[9];
    float* out = (float*)d_out;
    const int* srcA = ei;
    const int* dstA = ei + NEDGES;

    char* wsb = (char*)d_ws;
    size_t off = 0;
    auto alloc = [&](size_t elems) -> void* {
        void* p = (void*)(wsb + off);
        off += ((elems + 7) & ~(size_t)7) * 4;
        return p;
    };
    int* cnt = (int*)alloc(NNODES);
    int* rowptr = (int*)alloc(NNODES + 1);
    float* dinv = (float*)alloc(NNODES);
    int* scanBlk = (int*)alloc(64);
    int* scanOff = (int*)alloc(64);
    int* bcnt = (int*)alloc(256);
    int* bbase = (int*)alloc(256);
    int* gbkcur = (int*)alloc(256);
    float* stats = (float*)alloc(NSHARD * SHSTRIDE);  // per shard: [l*128]=sum, [512+l*128]=sq
    unsigned* ew = (unsigned*)alloc((size_t)NEDGES + 8 * NNODES);  // padded CSR src indices
    uint2* ebuf = (uint2*)alloc(2 * (size_t)NEDGES);               // bucket-major staging
    unsigned* xb = (unsigned*)alloc((size_t)(NNODES + 1) * 17);
    // union: A0 (fp32, N*36 words, layer-0 only) / Y (bf16, (N+1)*50 words, layers 1-3)
    float* A0 = (float*)alloc((size_t)(NNODES + 1) * 50);
    unsigned* Y = (unsigned*)A0;
    unsigned* Abf = (unsigned*)alloc((size_t)NNODES * 50);
    unsigned* Zb = (unsigned*)alloc((size_t)NNODES * 50);
    float* gbuf = (float*)alloc((size_t)NGRAPH * CH);
    (void)ws_size; (void)n_in; (void)in_sizes; (void)out_size;

    hipLaunchKernelGGL(k_init, dim3((NNODES + 255) / 256), dim3(256), 0, stream,
                       cnt, stats, gbuf);
    hipLaunchKernelGGL(k_hist, dim3((NEDGES + 255) / 256), dim3(256), 0, stream, dstA, cnt);
    hipLaunchKernelGGL(k_scan1, dim3(SCAN_BLOCKS), dim3(SCAN_TPB), 0, stream,
                       cnt, rowptr, scanBlk, dinv, bcnt);
    hipLaunchKernelGGL(k_scan2, dim3(1), dim3(64), 0, stream, scanBlk, scanOff, rowptr);
    hipLaunchKernelGGL(k_scan3, dim3(SCAN_BLOCKS), dim3(SCAN_TPB), 0, stream, rowptr, scanOff);
    hipLaunchKernelGGL(k_bscan, dim3(1), dim3(256), 0, stream, bcnt, bbase, gbkcur);
    hipLaunchKernelGGL(k_packx, dim3(((NNODES + 1) * 17 + 255) / 256), dim3(256), 0, stream,
                       x, xb, dinv);
    hipLaunchKernelGGL(k_bin, dim3((NEDGES + BEPW - 1) / BEPW), dim3(256), 0, stream,
                       srcA, dstA, gbkcur, ebuf);
    hipLaunchKernelGGL(k_place, dim3(NBUK), dim3(256), 0, stream, ebuf, bbase, rowptr, ew);

    // ---- layer 0 ----
    hipLaunchKernelGGL((k_gather<17, 68, 36, false>), dim3(12500), dim3(256), 0, stream,
                       xb, A0, rowptr, ew, dinv);
    hipLaunchKernelGGL(k_gemm0, dim3((NNODES + 63) / 64), dim3(512), 0, stream,
                       A0, W0, b, Zb, stats + 0 * 128, stats + 512 + 0 * 128);
    // ---- layers 1..3 ----
    for (int l = 1; l < 4; ++l) {
        float* ps = stats + (l - 1) * 128;
        float* pq = stats + 512 + (l - 1) * 128;
        hipLaunchKernelGGL(k_bnact, dim3(((NNODES + 1) * 50 + 255) / 256), dim3(256), 0, stream,
                           Zb, Y, ps, pq, gamma + (l - 1) * CH, beta + (l - 1) * CH, dinv);
        hipLaunchKernelGGL((k_gather<50, 200, 50, true>), dim3(12500), dim3(256), 0, stream,
                           Y, Abf, rowptr, ew, dinv);
        hipLaunchKernelGGL(k_gemm_ch, dim3((NNODES + 63) / 64), dim3(512), 0, stream,
                           Abf, Wrest + (l - 1) * 10000, b + l * CH, Zb,
                           stats + l * 128, stats + 512 + l * 128);
    }
    hipLaunchKernelGGL(k_pool, dim3(NGRAPH, 4), dim3(64), 0, stream, Zb, batch,
                       stats + 3 * 128, stats + 512 + 3 * 128, gamma + 3 * CH, beta + 3 * CH, gbuf);
    hipLaunchKernelGGL(k_out, dim3(NGRAPH), dim3(256), 0, stream, gbuf, Wout, bout, out);
}

// Round 4
// 447.095 us; speedup vs baseline: 1.2675x; 1.1597x over previous
//
#include <hip/hip_runtime.h>

#define NNODES 50000
#define NEDGES 800000
#define NGRAPH 500
#define CH 100
#define CIN0 33
#define BN_EPS 1e-5f
#define NSHARD 8
#define SHSTRIDE 1024   // floats per shard: [4 layers][sum128|sq128]
#define NBUK 196        // = ceil(NNODES/256); bucket b covers dst nodes [b*256, b*256+256)
#define BEPW 2048       // edges per workgroup in k_bin

#define SCAN_TPB 256
#define SCAN_IPT 4
#define SCAN_TILE (SCAN_TPB * SCAN_IPT)
#define SCAN_BLOCKS ((NNODES + SCAN_TILE - 1) / SCAN_TILE)

typedef __attribute__((ext_vector_type(8))) short short8;
typedef __attribute__((ext_vector_type(4))) float f32x4;

// pack two fp32 into (bf16(x) | bf16(y)<<16), round-to-nearest-even
__device__ inline unsigned pack_bf16(float x, float y) {
    unsigned xb = __float_as_uint(x);
    unsigned yb = __float_as_uint(y);
    xb += 0x7FFF + ((xb >> 16) & 1);
    yb += 0x7FFF + ((yb >> 16) & 1);
    return (xb >> 16) | (yb & 0xFFFF0000u);
}
__device__ inline float unp_lo(unsigned v) { return __uint_as_float(v << 16); }
__device__ inline float unp_hi(unsigned v) { return __uint_as_float(v & 0xFFFF0000u); }

// ---------------- init: zero counters + BN stat shards + pool accumulator ----------------
__global__ void k_init(int* __restrict__ cnt, float* __restrict__ stats,
                       float* __restrict__ gbuf) {
    int i = blockIdx.x * blockDim.x + threadIdx.x;
    if (i < NNODES) cnt[i] = 0;
    if (i < NGRAPH * CH) gbuf[i] = 0.f;   // NGRAPH*CH == NNODES
    if (i < NSHARD * SHSTRIDE) stats[i] = 0.f;
}

// ---------------- in-degree histogram over dst ----------------
__global__ void k_hist(const int* __restrict__ dst, int* __restrict__ cnt) {
    int e = blockIdx.x * blockDim.x + threadIdx.x;
    if (e < NEDGES) atomicAdd(&cnt[dst[e]], 1);
}

// ---------------- pack dinv[r]*x into bf16 rows of 17 uints (+1 zero sentinel row) ----------------
__global__ void k_packx(const float* __restrict__ x, unsigned* __restrict__ xb,
                        const float* __restrict__ dinv) {
    int i = blockIdx.x * blockDim.x + threadIdx.x;
    if (i >= (NNODES + 1) * 17) return;
    int r = i / 17, s = i - r * 17;
    if (r >= NNODES) { xb[i] = 0u; return; }
    float di = dinv[r];
    float a = di * x[r * CIN0 + 2 * s];
    float b = (2 * s + 1 < CIN0) ? di * x[r * CIN0 + 2 * s + 1] : 0.f;
    xb[i] = pack_bf16(a, b);
}

// ---------------- pack W^T (col-major, k-padded to 128) into bf16 hi + bf16 residual lo ----------------
// Wt[l][c][ku] : c in [0,112), ku = k/2 in [0,64). Zero outside 100x100.
__global__ void k_packw(const float* __restrict__ Wrest, unsigned* __restrict__ whi,
                        unsigned* __restrict__ wlo) {
    int i = blockIdx.x * blockDim.x + threadIdx.x;
    if (i >= 3 * 112 * 64) return;
    int l = i / 7168, rem = i % 7168;
    int c = rem >> 6, ku = rem & 63;
    int k0 = 2 * ku;
    float w0 = 0.f, w1 = 0.f;
    if (c < CH && k0 < CH) {
        w0 = Wrest[l * 10000 + k0 * CH + c];
        if (k0 + 1 < CH) w1 = Wrest[l * 10000 + (k0 + 1) * CH + c];
    }
    unsigned h = pack_bf16(w0, w1);
    whi[i] = h;
    wlo[i] = pack_bf16(w0 - unp_lo(h), w1 - unp_hi(h));
}

// ---------------- exclusive scan of padded counts -> rowptr; dinv; per-bucket edge counts ----------------
__global__ void k_scan1(const int* __restrict__ cnt, int* __restrict__ rowptr,
                        int* __restrict__ blkSums, float* __restrict__ dinv,
                        int* __restrict__ bcnt) {
    __shared__ int ts[SCAN_TPB];
    __shared__ int bsum[4];
    int tid = threadIdx.x;
    if (tid < 4) bsum[tid] = 0;
    int base = blockIdx.x * SCAN_TILE + tid * SCAN_IPT;
    int v[SCAN_IPT];
    int s = 0, cact = 0;
    #pragma unroll
    for (int j = 0; j < SCAN_IPT; ++j) {
        int i = base + j;
        int c = (i < NNODES) ? cnt[i] : 0;
        if (i < NNODES) dinv[i] = rsqrtf((float)(c + 1));
        v[j] = (c + 7) & ~7;   // pad each row to multiple of 8 edges
        s += v[j];
        cact += c;
    }
    ts[tid] = s;
    __syncthreads();
    atomicAdd(&bsum[(tid * SCAN_IPT) >> 8], cact);
    for (int off = 1; off < SCAN_TPB; off <<= 1) {
        int add = (tid >= off) ? ts[tid - off] : 0;
        __syncthreads();
        ts[tid] += add;
        __syncthreads();
    }
    int run = ts[tid] - s;
    #pragma unroll
    for (int j = 0; j < SCAN_IPT; ++j) {
        int i = base + j;
        if (i < NNODES) rowptr[i] = run;
        run += v[j];
    }
    if (tid == SCAN_TPB - 1) blkSums[blockIdx.x] = ts[tid];
    if (tid < 4) {
        int b = blockIdx.x * 4 + tid;
        if (b < NBUK) bcnt[b] = bsum[tid];
    }
}

__global__ void k_scan2(const int* __restrict__ blkSums, int* __restrict__ blkOff,
                        int* __restrict__ rowptr) {
    if (threadIdx.x == 0) {
        int run = 0;
        for (int i = 0; i < SCAN_BLOCKS; ++i) { blkOff[i] = run; run += blkSums[i]; }
        rowptr[NNODES] = run;
    }
}

__global__ void k_scan3(int* __restrict__ rowptr, const int* __restrict__ blkOff) {
    int off = blkOff[blockIdx.x];
    int base = blockIdx.x * SCAN_TILE + threadIdx.x * SCAN_IPT;
    #pragma unroll
    for (int j = 0; j < SCAN_IPT; ++j) {
        int i = base + j;
        if (i < NNODES) rowptr[i] += off;
    }
}

// ---------------- exclusive scan of bucket counts -> staging bases (+ working cursors) ----------------
__global__ void k_bscan(const int* __restrict__ bcnt, int* __restrict__ bbase,
                        int* __restrict__ gbkcur) {
    __shared__ int ts[256];
    int t = threadIdx.x;
    int v = (t < NBUK) ? bcnt[t] : 0;
    ts[t] = v;
    __syncthreads();
    for (int off = 1; off < 256; off <<= 1) {
        int a = (t >= off) ? ts[t - off] : 0;
        __syncthreads();
        ts[t] += a;
        __syncthreads();
    }
    int excl = ts[t] - v;
    if (t < NBUK) { bbase[t] = excl; gbkcur[t] = excl; }
    if (t == NBUK - 1) bbase[NBUK] = ts[t];
}

// ---------------- phase A: bin edges by dst-bucket into bucket-major staging ----------------
__global__ __launch_bounds__(256) void k_bin(const int* __restrict__ src,
                                             const int* __restrict__ dst,
                                             int* __restrict__ gbkcur,
                                             uint2* __restrict__ ebuf) {
    __shared__ int hist[256], ofs[256], lcnt[256], bbaseL[256];
    __shared__ int totS;
    __shared__ uint2 stage[BEPW];   // 16 KB
    int tid = threadIdx.x;
    hist[tid] = 0; lcnt[tid] = 0;
    __syncthreads();
    int e0 = blockIdx.x * BEPW;
    unsigned sv[8]; int dv[8]; bool ok[8];
    #pragma unroll
    for (int j = 0; j < 8; ++j) {
        int e = e0 + j * 256 + tid;
        ok[j] = e < NEDGES;
        sv[j] = ok[j] ? (unsigned)src[e] : 0u;
        dv[j] = ok[j] ? dst[e] : 0;
        if (ok[j]) atomicAdd(&hist[dv[j] >> 8], 1);
    }
    __syncthreads();
    int v = hist[tid];
    ofs[tid] = v;
    __syncthreads();
    for (int off = 1; off < 256; off <<= 1) {
        int a = (tid >= off) ? ofs[tid - off] : 0;
        __syncthreads();
        ofs[tid] += a;
        __syncthreads();
    }
    if (tid == 255) totS = ofs[255];
    int excl = ofs[tid] - v;
    __syncthreads();
    ofs[tid] = excl;
    if (tid < NBUK && v > 0) bbaseL[tid] = atomicAdd(&gbkcur[tid], v);
    __syncthreads();
    #pragma unroll
    for (int j = 0; j < 8; ++j) {
        if (ok[j]) {
            int b = dv[j] >> 8;
            int idx = atomicAdd(&lcnt[b], 1);
            stage[ofs[b] + idx] = make_uint2(sv[j], (unsigned)dv[j]);
        }
    }
    __syncthreads();
    int tot = totS;
    #pragma unroll
    for (int j = 0; j < 8; ++j) {
        int slot = j * 256 + tid;
        if (slot < tot) {
            uint2 p = stage[slot];
            int b = (int)(p.y >> 8);
            ebuf[bbaseL[b] + (slot - ofs[b])] = p;
        }
    }
}

// ---------------- phase B: place edges into padded CSR; LDS cursors; pad fill ----------------
__global__ __launch_bounds__(256) void k_place(const uint2* __restrict__ ebuf,
                                               const int* __restrict__ bbase,
                                               const int* __restrict__ rowptr,
                                               unsigned* __restrict__ ew) {
    __shared__ int lcur[256];
    int b = blockIdx.x, t = threadIdx.x;
    int lo = b * 256;
    int n = NNODES - lo; if (n > 256) n = 256;
    if (t < n) lcur[t] = rowptr[lo + t];
    __syncthreads();
    int e0 = bbase[b], e1 = bbase[b + 1];
    for (int e = e0 + t; e < e1; e += 256) {
        uint2 p = ebuf[e];
        int pos = atomicAdd(&lcur[p.y & 255], 1);
        ew[pos] = p.x;
    }
    __syncthreads();
    if (t < n) {
        int end = rowptr[lo + t + 1];
        for (int q = lcur[t]; q < end; ++q) ew[q] = NNODES;   // sentinel pads
    }
}

// ---------------- apply y = dinv * relu(BN(z)) in bf16, one streaming pass ----------------
__global__ __launch_bounds__(256) void k_bnact(
    const unsigned* __restrict__ Zb, unsigned* __restrict__ Y,
    const float* __restrict__ gsum, const float* __restrict__ gsq,
    const float* __restrict__ gamma, const float* __restrict__ beta,
    const float* __restrict__ dinv) {
    int i = blockIdx.x * blockDim.x + threadIdx.x;
    if (i >= (NNODES + 1) * 50) return;
    int node = i / 50, c = i - node * 50;
    if (node >= NNODES) { Y[i] = 0u; return; }
    float sx = 0.f, sy = 0.f, qx = 0.f, qy = 0.f;
    #pragma unroll
    for (int sh = 0; sh < NSHARD; ++sh) {
        float2 s2 = ((const float2*)(gsum + sh * SHSTRIDE))[c];
        float2 q2 = ((const float2*)(gsq + sh * SHSTRIDE))[c];
        sx += s2.x; sy += s2.y; qx += q2.x; qy += q2.y;
    }
    constexpr float invN = 1.f / NNODES;
    float2 g2 = ((const float2*)gamma)[c];
    float2 b2 = ((const float2*)beta)[c];
    float mx = sx * invN, my = sy * invN;
    float vx = qx * invN - mx * mx, vy = qy * invN - my * my;
    float scx = g2.x * rsqrtf(vx + BN_EPS), shx = b2.x - mx * scx;
    float scy = g2.y * rsqrtf(vy + BN_EPS), shy = b2.y - my * scy;
    float di = dinv[node];
    unsigned v = Zb[i];
    float yx = fmaxf(unp_lo(v) * scx + shx, 0.f) * di;
    float yy = fmaxf(unp_hi(v) * scy + shy, 0.f) * di;
    Y[i] = pack_bf16(yx, yy);
}

// ---------------- pure gather-add aggregate over pre-scaled bf16 rows ----------------
template<int CPACK, int RB, int OS, bool OBF>
__global__ __launch_bounds__(256) void k_gather(
    const unsigned* __restrict__ h, void* __restrict__ aout,
    const int* __restrict__ rowptr, const unsigned* __restrict__ ew,
    const float* __restrict__ dinv) {
    int node = (blockIdx.x * 256 + threadIdx.x) >> 6;
    int lane = threadIdx.x & 63;
    if (node >= NNODES) return;
    int p0 = __builtin_amdgcn_readfirstlane(rowptr[node]);
    int p1 = __builtin_amdgcn_readfirstlane(rowptr[node + 1]);
    float di = dinv[node];
    bool act = lane < CPACK;
    unsigned l4 = (unsigned)(lane << 2);
    const char* __restrict__ hb = (const char*)h;
    float ax = 0.f, ay = 0.f;
    if (act) {
        unsigned hv = h[node * CPACK + lane];   // self term (already dinv-scaled)
        ax = unp_lo(hv); ay = unp_hi(hv);
    }
    const uint4* __restrict__ E4 = (const uint4*)(ew + p0);   // 16B-aligned (p0 mult of 8)
    int n8 = (p1 - p0) >> 3;
    #pragma unroll 2
    for (int q = 0; q < n8; ++q) {
        uint4 ea = E4[2 * q];
        uint4 eb = E4[2 * q + 1];
        if (act) {
            unsigned v0 = *(const unsigned*)(hb + (ea.x * (unsigned)RB + l4));
            unsigned v1 = *(const unsigned*)(hb + (ea.y * (unsigned)RB + l4));
            unsigned v2 = *(const unsigned*)(hb + (ea.z * (unsigned)RB + l4));
            unsigned v3 = *(const unsigned*)(hb + (ea.w * (unsigned)RB + l4));
            unsigned v4 = *(const unsigned*)(hb + (eb.x * (unsigned)RB + l4));
            unsigned v5 = *(const unsigned*)(hb + (eb.y * (unsigned)RB + l4));
            unsigned v6 = *(const unsigned*)(hb + (eb.z * (unsigned)RB + l4));
            unsigned v7 = *(const unsigned*)(hb + (eb.w * (unsigned)RB + l4));
            ax += unp_lo(v0); ay += unp_hi(v0);
            ax += unp_lo(v1); ay += unp_hi(v1);
            ax += unp_lo(v2); ay += unp_hi(v2);
            ax += unp_lo(v3); ay += unp_hi(v3);
            ax += unp_lo(v4); ay += unp_hi(v4);
            ax += unp_lo(v5); ay += unp_hi(v5);
            ax += unp_lo(v6); ay += unp_hi(v6);
            ax += unp_lo(v7); ay += unp_hi(v7);
        }
    }
    float ox = di * ax, oy = di * ay;
    if constexpr (OBF) {
        if (lane < OS)
            ((unsigned*)aout)[(size_t)node * OS + lane] = pack_bf16(ox, oy);
    } else {
        if (lane < (OS + 1) / 2)
            ((float2*)((float*)aout + (size_t)node * OS))[lane] = make_float2(ox, oy);
    }
}

// ---------------- CH-layer GEMM via MFMA (512 thr = 8 waves; W in bf16 hi+lo) ----------------
// Z[64][100] = A[64][100] @ W[100][100] + bias; A bf16 rows padded to 128 (64 uints).
// LDS: A 64x128 bf16 (16 KB) + Wt hi/lo 112x128 bf16 (28 KB each), XOR-swizzled
// (byte ^= (row&7)<<4 -> 2-way bank aliasing, free). Wave w: m-tile (w&3), n-half (w>>2).
// mfma_f32_16x16x32_bf16: A row=lane&15, k=(lane>>4)*8+r ; B col=lane&15, same k;
// D col=lane&15, row=(lane>>4)*4+reg [m89-verified].
__global__ __launch_bounds__(512) void k_gemm_ch(
    const unsigned* __restrict__ Ab, const unsigned* __restrict__ Whi,
    const unsigned* __restrict__ Wlo, const float* __restrict__ bias,
    unsigned* __restrict__ Zb, float* __restrict__ gsum, float* __restrict__ gsq) {
    __shared__ __align__(16) unsigned char aS[64 * 256];    // 16 KB
    __shared__ __align__(16) unsigned char wH[112 * 256];   // 28 KB
    __shared__ __align__(16) unsigned char wL[112 * 256];   // 28 KB
    __shared__ float sSum[CH], sSq[CH];
    int tid = threadIdx.x;
    for (int i = tid; i < CH; i += 512) { sSum[i] = 0.f; sSq[i] = 0.f; }
    int row0 = blockIdx.x * 64;
    for (int idx = tid; idx < 64 * 16; idx += 512) {
        int r = idx >> 4, j = idx & 15;
        uint4 v = make_uint4(0u, 0u, 0u, 0u);
        if (row0 + r < NNODES) v = *(const uint4*)(Ab + (size_t)(row0 + r) * 64 + j * 4);
        *(uint4*)(aS + ((r * 256 + j * 16) ^ ((r & 7) << 4))) = v;
    }
    for (int idx = tid; idx < 112 * 16; idx += 512) {
        int c = idx >> 4, j = idx & 15;
        unsigned sw = (unsigned)((c * 256 + j * 16) ^ ((c & 7) << 4));
        *(uint4*)(wH + sw) = *(const uint4*)(Whi + c * 64 + j * 4);
        *(uint4*)(wL + sw) = *(const uint4*)(Wlo + c * 64 + j * 4);
    }
    __syncthreads();
    int w = tid >> 6, lane = tid & 63;
    int wm = w & 3, wh = w >> 2;           // m-tile, n-half (wh=0: nt 0..3, wh=1: nt 4..6)
    int lr = lane & 15, lg = lane >> 4;
    f32x4 acc[4];
    #pragma unroll
    for (int nt = 0; nt < 4; ++nt) acc[nt] = (f32x4){0.f, 0.f, 0.f, 0.f};
    int ar = wm * 16 + lr;
    unsigned aswz = (unsigned)((ar & 7) << 4);
    #pragma unroll
    for (int ks = 0; ks < 4; ++ks) {
        short8 af = *(const short8*)(aS + ((unsigned)(ar * 256 + ks * 64 + lg * 16) ^ aswz));
        #pragma unroll
        for (int nt = 0; nt < 4; ++nt) {
            if (wh && nt == 3) continue;   // only 7 n-tiles total
            int c = (wh * 4 + nt) * 16 + lr;
            unsigned wb = (unsigned)((c * 256 + ks * 64 + lg * 16) ^ ((c & 7) << 4));
            short8 bh = *(const short8*)(wH + wb);
            short8 bl = *(const short8*)(wL + wb);
            acc[nt] = __builtin_amdgcn_mfma_f32_16x16x32_bf16(af, bh, acc[nt], 0, 0, 0);
            acc[nt] = __builtin_amdgcn_mfma_f32_16x16x32_bf16(af, bl, acc[nt], 0, 0, 0);
        }
    }
    // epilogue: bias, packed bf16 store, BN stats
    #pragma unroll
    for (int nt = 0; nt < 4; ++nt) {
        if (wh && nt == 3) continue;
        int c = (wh * 4 + nt) * 16 + lr;
        bool cok = c < CH;
        float bcol = cok ? bias[c] : 0.f;
        float s = 0.f, q = 0.f;
        #pragma unroll
        for (int r = 0; r < 4; ++r) {
            int row = row0 + wm * 16 + lg * 4 + r;
            float z = acc[nt][r] + bcol;
            float zo = __shfl_xor(z, 1);
            if (cok && row < NNODES) {
                if ((lane & 1) == 0)
                    Zb[(size_t)row * 50 + (c >> 1)] = pack_bf16(z, zo);
                s += z; q += z * z;
            }
        }
        s += __shfl_xor(s, 16); s += __shfl_xor(s, 32);
        q += __shfl_xor(q, 16); q += __shfl_xor(q, 32);
        if (lane < 16 && cok) { atomicAdd(&sSum[c], s); atomicAdd(&sSq[c], q); }
    }
    __syncthreads();
    int sh = (blockIdx.x & (NSHARD - 1)) * SHSTRIDE;
    if (tid < CH) { atomicAdd(&gsum[sh + tid], sSum[tid]); atomicAdd(&gsq[sh + tid], sSq[tid]); }
}

// ---------------- layer-0 GEMM (512 thr, 4x4 tile, K=36, unroll-capped) ----------------
__global__ __launch_bounds__(512) void k_gemm0(
    const float* __restrict__ A, const float* __restrict__ W, const float* __restrict__ bias,
    unsigned* __restrict__ Zb, float* __restrict__ gsum, float* __restrict__ gsq) {
    constexpr int K = CIN0, KP = 36;
    __shared__ __align__(16) float wS[KP * CH];   // 14.4 KB
    __shared__ __align__(16) float aS[64 * KP];   // 9.2 KB
    __shared__ float sSum[CH], sSq[CH];
    int tid = threadIdx.x;
    for (int i = tid; i < CH; i += 512) { sSum[i] = 0.f; sSq[i] = 0.f; }
    for (int i = tid; i < KP * CH; i += 512) wS[i] = (i < K * CH) ? W[i] : 0.f;
    int row0 = blockIdx.x * 64;
    {
        const float* As = A + (size_t)row0 * KP;
        int maxI = (NNODES - row0) * KP;
        for (int i = tid; i < 64 * KP; i += 512) aS[i] = (i < maxI) ? As[i] : 0.f;
    }
    __syncthreads();
    if (tid < 400) {
        int ct = tid % 25, rt = tid / 25;  // ct 0..24, rt 0..15
        int c0 = ct * 4, r0 = rt * 4;
        float acc[4][4] = {};
        #pragma unroll 1
        for (int k = 0; k < KP; k += 4) {
            float4 w0 = *(const float4*)&wS[(k + 0) * CH + c0];
            float4 w1 = *(const float4*)&wS[(k + 1) * CH + c0];
            float4 w2 = *(const float4*)&wS[(k + 2) * CH + c0];
            float4 w3 = *(const float4*)&wS[(k + 3) * CH + c0];
            #pragma unroll
            for (int j = 0; j < 4; ++j) {
                float4 av = *(const float4*)&aS[(r0 + j) * KP + k];
                acc[j][0] += av.x * w0.x + av.y * w1.x + av.z * w2.x + av.w * w3.x;
                acc[j][1] += av.x * w0.y + av.y * w1.y + av.z * w2.y + av.w * w3.y;
                acc[j][2] += av.x * w0.z + av.y * w1.z + av.z * w2.z + av.w * w3.z;
                acc[j][3] += av.x * w0.w + av.y * w1.w + av.z * w2.w + av.w * w3.w;
            }
        }
        float4 bv = *(const float4*)&bias[c0];
        float cs0 = 0, cs1 = 0, cs2 = 0, cs3 = 0, cq0 = 0, cq1 = 0, cq2 = 0, cq3 = 0;
        #pragma unroll
        for (int j = 0; j < 4; ++j) {
            int r = row0 + r0 + j;
            if (r < NNODES) {
                float z0 = acc[j][0] + bv.x, z1 = acc[j][1] + bv.y;
                float z2 = acc[j][2] + bv.z, z3 = acc[j][3] + bv.w;
                *(uint2*)&Zb[(size_t)r * 50 + (c0 >> 1)] =
                    make_uint2(pack_bf16(z0, z1), pack_bf16(z2, z3));
                cs0 += z0; cs1 += z1; cs2 += z2; cs3 += z3;
                cq0 += z0 * z0; cq1 += z1 * z1; cq2 += z2 * z2; cq3 += z3 * z3;
            }
        }
        atomicAdd(&sSum[c0], cs0); atomicAdd(&sSum[c0 + 1], cs1);
        atomicAdd(&sSum[c0 + 2], cs2); atomicAdd(&sSum[c0 + 3], cs3);
        atomicAdd(&sSq[c0], cq0); atomicAdd(&sSq[c0 + 1], cq1);
        atomicAdd(&sSq[c0 + 2], cq2); atomicAdd(&sSq[c0 + 3], cq3);
    }
    __syncthreads();
    int sh = (blockIdx.x & (NSHARD - 1)) * SHSTRIDE;
    if (tid < CH) { atomicAdd(&gsum[sh + tid], sSum[tid]); atomicAdd(&gsq[sh + tid], sSq[tid]); }
}

// ---------------- global_add_pool of BN(z) from bf16 Z; 4 row-chunks per graph ----------------
__global__ void k_pool(const unsigned* __restrict__ Zl, const int* __restrict__ batch,
                       const float* __restrict__ gsum, const float* __restrict__ gsq,
                       const float* __restrict__ gamma, const float* __restrict__ beta,
                       float* __restrict__ g) {
    int gid = blockIdx.x;
    int part = blockIdx.y;
    int lo = 0, hi = NNODES;
    while (lo < hi) { int mid = (lo + hi) >> 1; if (batch[mid] < gid) lo = mid + 1; else hi = mid; }
    int start = lo;
    hi = NNODES;
    while (lo < hi) { int mid = (lo + hi) >> 1; if (batch[mid] < gid + 1) lo = mid + 1; else hi = mid; }
    int end = lo;
    int len = end - start;
    int cb = (len + 3) >> 2;
    int s = start + part * cb;
    int e = s + cb; if (e > end) e = end;
    if (s >= e) return;
    int t = threadIdx.x;
    if (t >= 50) return;
    float su = 0.f, sv = 0.f, qu = 0.f, qv = 0.f;
    #pragma unroll
    for (int sh = 0; sh < NSHARD; ++sh) {
        float2 s2 = ((const float2*)(gsum + sh * SHSTRIDE))[t];
        float2 q2 = ((const float2*)(gsq + sh * SHSTRIDE))[t];
        su += s2.x; sv += s2.y; qu += q2.x; qv += q2.y;
    }
    constexpr float invN = 1.f / NNODES;
    float2 g2 = ((const float2*)gamma)[t];
    float2 b2 = ((const float2*)beta)[t];
    float mx = su * invN, my = sv * invN;
    float vx = qu * invN - mx * mx, vy = qv * invN - my * my;
    float scx = g2.x * rsqrtf(vx + BN_EPS), shx = b2.x - mx * scx;
    float scy = g2.y * rsqrtf(vy + BN_EPS), shy = b2.y - my * scy;
    float sx = 0.f, sy = 0.f;
    for (int r = s; r < e; ++r) {
        unsigned v = Zl[(size_t)r * 50 + t];
        sx += unp_lo(v); sy += unp_hi(v);
    }
    float n = (float)(e - s);
    atomicAdd(&g[gid * CH + 2 * t], sx * scx + n * shx);
    atomicAdd(&g[gid * CH + 2 * t + 1], sy * scy + n * shy);
}

// ---------------- out = leakyrelu(g @ Wout + bout, 0.1) ----------------
__global__ __launch_bounds__(256) void k_out(const float* __restrict__ g,
                                             const float* __restrict__ Wout,
                                             const float* __restrict__ bout,
                                             float* __restrict__ out) {
    __shared__ float gS[CH];
    int gid = blockIdx.x, tid = threadIdx.x;
    if (tid < CH) gS[tid] = g[gid * CH + tid];
    __syncthreads();
    if (tid >= 200) return;
    float acc = bout[tid];
    for (int k = 0; k < CH; ++k) acc += gS[k] * Wout[k * 200 + tid];
    out[gid * 200 + tid] = acc > 0.f ? acc : 0.1f * acc;
}

extern "C" void kernel_launch(void* const* d_in, const int* in_sizes, int n_in,
                              void* d_out, int out_size, void* d_ws, size_t ws_size,
                              hipStream_t stream) {
    const float* x = (const float*)d_in[0];
    const int* ei = (const int*)d_in[1];
    const int* batch = (const int*)d_in[2];
    const float* W0 = (const float*)d_in[3];
    const float* Wrest = (const float*)d_in[4];
    const float* b = (const float*)d_in[5];
    const float* gamma = (const float*)d_in[6];
    const float* beta = (const float*)d_in[7];
    const float* Wout = (const float*)d_in[8];
    const float* bout = (const float*)d_in[9];
    float* out = (float*)d_out;
    const int* srcA = ei;
    const int* dstA = ei + NEDGES;

    char* wsb = (char*)d_ws;
    size_t off = 0;
    auto alloc = [&](size_t elems) -> void* {
        void* p = (void*)(wsb + off);
        off += ((elems + 7) & ~(size_t)7) * 4;
        return p;
    };
    int* cnt = (int*)alloc(NNODES);
    int* rowptr = (int*)alloc(NNODES + 1);
    float* dinv = (float*)alloc(NNODES);
    int* scanBlk = (int*)alloc(64);
    int* scanOff = (int*)alloc(64);
    int* bcnt = (int*)alloc(256);
    int* bbase = (int*)alloc(256);
    int* gbkcur = (int*)alloc(256);
    float* stats = (float*)alloc(NSHARD * SHSTRIDE);
    unsigned* ew = (unsigned*)alloc((size_t)NEDGES + 8 * NNODES);  // padded CSR src indices
    uint2* ebuf = (uint2*)alloc(2 * (size_t)NEDGES);               // bucket-major staging
    unsigned* xb = (unsigned*)alloc((size_t)(NNODES + 1) * 17);
    unsigned* wthi = (unsigned*)alloc(3 * 112 * 64);
    unsigned* wtlo = (unsigned*)alloc(3 * 112 * 64);
    // union: A0 (fp32, N*36 words, layer-0 only) / Y (bf16, (N+1)*50 words, layers 1-3)
    float* A0 = (float*)alloc((size_t)(NNODES + 1) * 50);
    unsigned* Y = (unsigned*)A0;
    unsigned* Abf = (unsigned*)alloc((size_t)NNODES * 64);   // bf16 rows padded to 128ch
    unsigned* Zb = (unsigned*)alloc((size_t)NNODES * 50);
    float* gbuf = (float*)alloc((size_t)NGRAPH * CH);
    (void)ws_size; (void)n_in; (void)in_sizes; (void)out_size;

    hipLaunchKernelGGL(k_init, dim3((NNODES + 255) / 256), dim3(256), 0, stream,
                       cnt, stats, gbuf);
    hipLaunchKernelGGL(k_packw, dim3((3 * 112 * 64 + 255) / 256), dim3(256), 0, stream,
                       Wrest, wthi, wtlo);
    hipLaunchKernelGGL(k_hist, dim3((NEDGES + 255) / 256), dim3(256), 0, stream, dstA, cnt);
    hipLaunchKernelGGL(k_scan1, dim3(SCAN_BLOCKS), dim3(SCAN_TPB), 0, stream,
                       cnt, rowptr, scanBlk, dinv, bcnt);
    hipLaunchKernelGGL(k_scan2, dim3(1), dim3(64), 0, stream, scanBlk, scanOff, rowptr);
    hipLaunchKernelGGL(k_scan3, dim3(SCAN_BLOCKS), dim3(SCAN_TPB), 0, stream, rowptr, scanOff);
    hipLaunchKernelGGL(k_bscan, dim3(1), dim3(256), 0, stream, bcnt, bbase, gbkcur);
    hipLaunchKernelGGL(k_packx, dim3(((NNODES + 1) * 17 + 255) / 256), dim3(256), 0, stream,
                       x, xb, dinv);
    hipLaunchKernelGGL(k_bin, dim3((NEDGES + BEPW - 1) / BEPW), dim3(256), 0, stream,
                       srcA, dstA, gbkcur, ebuf);
    hipLaunchKernelGGL(k_place, dim3(NBUK), dim3(256), 0, stream, ebuf, bbase, rowptr, ew);

    // ---- layer 0 ----
    hipLaunchKernelGGL((k_gather<17, 68, 36, false>), dim3(12500), dim3(256), 0, stream,
                       xb, A0, rowptr, ew, dinv);
    hipLaunchKernelGGL(k_gemm0, dim3((NNODES + 63) / 64), dim3(512), 0, stream,
                       A0, W0, b, Zb, stats + 0 * 128, stats + 512 + 0 * 128);
    // ---- layers 1..3 ----
    for (int l = 1; l < 4; ++l) {
        float* ps = stats + (l - 1) * 128;
        float* pq = stats + 512 + (l - 1) * 128;
        hipLaunchKernelGGL(k_bnact, dim3(((NNODES + 1) * 50 + 255) / 256), dim3(256), 0, stream,
                           Zb, Y, ps, pq, gamma + (l - 1) * CH, beta + (l - 1) * CH, dinv);
        hipLaunchKernelGGL((k_gather<50, 200, 64, true>), dim3(12500), dim3(256), 0, stream,
                           Y, Abf, rowptr, ew, dinv);
        hipLaunchKernelGGL(k_gemm_ch, dim3((NNODES + 63) / 64), dim3(512), 0, stream,
                           Abf, wthi + (l - 1) * 7168, wtlo + (l - 1) * 7168, b + l * CH, Zb,
                           stats + l * 128, stats + 512 + l * 128);
    }
    hipLaunchKernelGGL(k_pool, dim3(NGRAPH, 4), dim3(64), 0, stream, Zb, batch,
                       stats + 3 * 128, stats + 512 + 3 * 128, gamma + 3 * CH, beta + 3 * CH, gbuf);
    hipLaunchKernelGGL(k_out, dim3(NGRAPH), dim3(256), 0, stream, gbuf, Wout, bout, out);
}